// Round 9
// baseline (195.858 us; speedup 1.0000x reference)
//
#include <hip/hip_runtime.h>
#include <hip/hip_bf16.h>

#define N_NODES 50000
#define N_EDGES 600000
#define NC 10
#define GB ((N_NODES + 63) / 64)

typedef __attribute__((ext_vector_type(8))) __bf16 bf16x8;
typedef __attribute__((ext_vector_type(8))) unsigned short u16x8;
typedef __attribute__((ext_vector_type(4))) float f32x4;

__device__ __forceinline__ unsigned short f2bf(float f) {
    unsigned u = __float_as_uint(f);
    u += 0x7fff + ((u >> 16) & 1);           // round-to-nearest-even
    return (unsigned short)(u >> 16);
}
__device__ __forceinline__ int rfl(int x) { return __builtin_amdgcn_readfirstlane(x); }
__device__ __forceinline__ float rflf(float x) {
    return __uint_as_float(__builtin_amdgcn_readfirstlane(__float_as_uint(x)));
}

// ---------------- zero helper ----------------
__global__ void k_zero(int4* __restrict__ p, int n4) {
    int i = blockIdx.x * blockDim.x + threadIdx.x;
    if (i < n4) p[i] = make_int4(0, 0, 0, 0);
}

// ---------------- prep: W transposes + edge count (fused, independent) ------
__global__ void k_prep(const float* __restrict__ W1, const float* __restrict__ W2,
                       unsigned short* __restrict__ wt1, unsigned short* __restrict__ wt2,
                       const int4* __restrict__ dst4, int* __restrict__ cnt,
                       int4* __restrict__ ord4) {
    int b = blockIdx.x;
    if (b < 128) {
        const float* W = (b < 64) ? W1 : W2;
        unsigned short* Wt = (b < 64) ? wt1 : wt2;
        int i = (b & 63) * 256 + threadIdx.x;    // 0..16383
        int n = i >> 7, k = i & 127;
        Wt[n * 128 + k] = f2bf(W[k * 128 + n]);
    } else {
        int i = (b - 128) * 256 + threadIdx.x;
        if (i < N_EDGES / 4) {
            int4 d = dst4[i];
            int4 o;
            o.x = atomicAdd(&cnt[d.x], 1);
            o.y = atomicAdd(&cnt[d.y], 1);
            o.z = atomicAdd(&cnt[d.z], 1);
            o.w = atomicAdd(&cnt[d.w], 1);
            ord4[i] = o;
        }
    }
}

// ---------------- exclusive scan (3 kernels) ----------------
__global__ void k_scan1(const int* __restrict__ cnt, int* __restrict__ rowptr,
                        int* __restrict__ bsum, int n) {
    __shared__ int sh[256];
    int t = threadIdx.x;
    int i = blockIdx.x * 256 + t;
    int v = (i < n) ? cnt[i] : 0;
    sh[t] = v;
    __syncthreads();
    for (int off = 1; off < 256; off <<= 1) {
        int x = 0;
        if (t >= off) x = sh[t - off];
        __syncthreads();
        sh[t] += x;
        __syncthreads();
    }
    if (i < n) rowptr[i] = sh[t] - v;
    if (t == 255) bsum[blockIdx.x] = sh[255];
}

__global__ void k_scan2(int* __restrict__ bsum, int nb) {
    __shared__ int sh[256];
    int t = threadIdx.x;
    int v = (t < nb) ? bsum[t] : 0;
    sh[t] = v;
    __syncthreads();
    for (int off = 1; off < 256; off <<= 1) {
        int x = 0;
        if (t >= off) x = sh[t - off];
        __syncthreads();
        sh[t] += x;
        __syncthreads();
    }
    if (t < nb) bsum[t] = sh[t] - v;
}

__global__ void k_scan3(int* __restrict__ rowptr, const int* __restrict__ bsum, int n) {
    int t = threadIdx.x;
    int i = blockIdx.x * 256 + t;
    if (i < n) rowptr[i] += bsum[blockIdx.x];
    if (blockIdx.x == 0 && t == 0) rowptr[n] = N_EDGES;
}

// ---------------- shared GEMM body (MFMA, bf16) ----------------
template <int FP32IN>
__device__ __forceinline__ void gemm_body(unsigned short* Al, unsigned short* Bl,
                                          const void* __restrict__ Xin,
                                          const unsigned short* __restrict__ Wt,
                                          unsigned short* __restrict__ Yb,
                                          int M, int row0) {
    int t = threadIdx.x;
    for (int i = t; i < 2048; i += 256) {
        int r = i >> 4, q = i & 15;
        *(u16x8*)(Bl + r * 128 + ((q ^ (r & 7)) << 3)) =
            *(const u16x8*)(Wt + r * 128 + (q << 3));
    }
    for (int i = t; i < 1024; i += 256) {
        int r = i >> 4, q = i & 15;
        int gr = row0 + r;
        u16x8 v;
        if (FP32IN) {
            const float* X = (const float*)Xin;
            if (gr < M) {
                float4 f0 = *(const float4*)(X + (size_t)gr * 128 + (q << 3));
                float4 f1 = *(const float4*)(X + (size_t)gr * 128 + (q << 3) + 4);
                v[0] = f2bf(f0.x); v[1] = f2bf(f0.y); v[2] = f2bf(f0.z); v[3] = f2bf(f0.w);
                v[4] = f2bf(f1.x); v[5] = f2bf(f1.y); v[6] = f2bf(f1.z); v[7] = f2bf(f1.w);
            } else {
#pragma unroll
                for (int j = 0; j < 8; ++j) v[j] = 0;
            }
        } else {
            const unsigned short* X = (const unsigned short*)Xin;
            if (gr < M) {
                v = *(const u16x8*)(X + (size_t)gr * 128 + (q << 3));
            } else {
#pragma unroll
                for (int j = 0; j < 8; ++j) v[j] = 0;
            }
        }
        *(u16x8*)(Al + r * 128 + ((q ^ (r & 7)) << 3)) = v;
    }
    __syncthreads();

    int l  = t & 63;
    int w  = t >> 6;
    int ar = (w << 4) + (l & 15);
    int kq = l >> 4;

    bf16x8 af[4];
#pragma unroll
    for (int s = 0; s < 4; ++s) {
        int g = ((s << 2) + kq) ^ (l & 7);
        af[s] = *(const bf16x8*)(Al + ar * 128 + (g << 3));
    }

    f32x4 acc[8];
#pragma unroll
    for (int c = 0; c < 8; ++c)
#pragma unroll
        for (int j = 0; j < 4; ++j) acc[c][j] = 0.0f;

#pragma unroll
    for (int c = 0; c < 8; ++c) {
        int br = (c << 4) + (l & 15);
#pragma unroll
        for (int s = 0; s < 4; ++s) {
            int g = ((s << 2) + kq) ^ (l & 7);
            bf16x8 bf = *(const bf16x8*)(Bl + br * 128 + (g << 3));
            acc[c] = __builtin_amdgcn_mfma_f32_16x16x32_bf16(af[s], bf, acc[c], 0, 0, 0);
        }
    }

    int orow = row0 + (w << 4) + ((l >> 4) << 2);
    int ocol = l & 15;
#pragma unroll
    for (int c = 0; c < 8; ++c) {
#pragma unroll
        for (int j = 0; j < 4; ++j) {
            int r = orow + j;
            if (r < M) Yb[(size_t)r * 128 + (c << 4) + ocol] = f2bf(acc[c][j]);
        }
    }
}

// ---------------- fused: GEMM1 (fp32 x) + CSR scatter (independent) ---------
__global__ __launch_bounds__(256) void k_sg(const float* __restrict__ X,
                                            const unsigned short* __restrict__ Wt,
                                            unsigned short* __restrict__ Yb, int M,
                                            const int* __restrict__ src,
                                            const int* __restrict__ dst,
                                            const float* __restrict__ ew,
                                            const int* __restrict__ ord,
                                            const int* __restrict__ rowptr,
                                            int* __restrict__ esrc,
                                            float* __restrict__ ew2) {
    __shared__ unsigned short Al[64 * 128];
    __shared__ unsigned short Bl[128 * 128];
    if (blockIdx.x < GB) {
        gemm_body<1>(Al, Bl, X, Wt, Yb, M, blockIdx.x * 64);
    } else {
        int e = (blockIdx.x - GB) * 256 + threadIdx.x;
        if (e < N_EDGES) {
            int pos = rowptr[dst[e]] + ord[e];
            esrc[pos] = src[e];
            ew2[pos]  = ew[e];
        }
    }
}

// ---------------- standalone GEMM (bf16 in, layer 2) ----------------
__global__ __launch_bounds__(256) void k_gemm_mfma(const unsigned short* __restrict__ Xb,
                                                   const unsigned short* __restrict__ Wt,
                                                   unsigned short* __restrict__ Yb, int M) {
    __shared__ unsigned short Al[64 * 128];
    __shared__ unsigned short Bl[128 * 128];
    gemm_body<0>(Al, Bl, Xb, Wt, Yb, M, blockIdx.x * 64);
}

// ---------------- per-node degree -> dinv ----------------
__global__ void k_deg(const int* __restrict__ rowptr, const float* __restrict__ ew2,
                      float* __restrict__ dinv) {
    int i = blockIdx.x * blockDim.x + threadIdx.x;
    if (i >= N_NODES) return;
    int p1 = rowptr[i + 1];
    float s = 1.0f;
    for (int p = rowptr[i]; p < p1; ++p) s += ew2[p];
    dinv[i] = rsqrtf(s);
}

// ---------------- per-node edge norms ----------------
__global__ void k_norm(const int* __restrict__ rowptr, const int* __restrict__ esrc,
                       const float* __restrict__ ew2, const float* __restrict__ dinv,
                       float* __restrict__ enorm) {
    int i = blockIdx.x * blockDim.x + threadIdx.x;
    if (i >= N_NODES) return;
    float di = dinv[i];
    int p  = rowptr[i];
    int p1 = rowptr[i + 1];
    for (; p + 4 <= p1; p += 4) {
        int s0 = esrc[p], s1 = esrc[p+1], s2 = esrc[p+2], s3 = esrc[p+3];
        float d0 = dinv[s0], d1 = dinv[s1], d2 = dinv[s2], d3 = dinv[s3];
        enorm[p]   = d0 * ew2[p]   * di;
        enorm[p+1] = d1 * ew2[p+1] * di;
        enorm[p+2] = d2 * ew2[p+2] * di;
        enorm[p+3] = d3 * ew2[p+3] * di;
    }
    for (; p < p1; ++p) enorm[p] = dinv[esrc[p]] * ew2[p] * di;
}

// ---------------- aggregation: 4 rows per gather instruction ----------------
// Wave = 1 node. 16-lane group g handles one edge per step; lane holds 8 feats
// (16B) of that edge's source row. One dwordx4 gather fetches 4 rows.
// Metadata via SGPR loads; self-loop folded in as virtual edge idx==cnt.
// MODE 0: out = relu(agg + bias) packed bf16; MODE 1: fused classifier.
template <int MODE>
__global__ __launch_bounds__(256) void k_agg(const unsigned short* __restrict__ hb,
                                             const int* __restrict__ rowptr,
                                             const int* __restrict__ esrc,
                                             const float* __restrict__ enorm,
                                             const float* __restrict__ dinv,
                                             const float* __restrict__ bias,
                                             const float* __restrict__ Wc,
                                             const float* __restrict__ bc,
                                             float* __restrict__ out) {
    int wid  = (blockIdx.x * blockDim.x + threadIdx.x) >> 6;
    int lane = threadIdx.x & 63;
    if (wid >= N_NODES) return;
    wid = rfl(wid);
    int p0  = rfl(rowptr[wid]);
    int cnt = rfl(rowptr[wid + 1]) - p0;
    float di  = rflf(dinv[wid]);
    float di2 = di * di;
    int g = lane >> 4;     // edge slot within step
    int q = lane & 15;     // 16B feature slice

    bool g0 = (g == 0), g1 = (g == 1), g2 = (g == 2);

    float acc[8];
#pragma unroll
    for (int j = 0; j < 8; ++j) acc[j] = 0.f;

    int items = cnt + 1;   // + virtual self edge at index cnt
    int base = 0;

#define STEP_META(B, SS, WW)                                                    \
    {                                                                           \
        int i0 = p0 + (B);                                                      \
        int e0 = min(i0,     N_EDGES - 1), e1 = min(i0 + 1, N_EDGES - 1);       \
        int e2 = min(i0 + 2, N_EDGES - 1), e3 = min(i0 + 3, N_EDGES - 1);       \
        int   s0 = rfl(esrc[e0]),  s1 = rfl(esrc[e1]);                          \
        int   s2 = rfl(esrc[e2]),  s3 = rfl(esrc[e3]);                          \
        float w0 = rflf(enorm[e0]), w1 = rflf(enorm[e1]);                       \
        float w2 = rflf(enorm[e2]), w3 = rflf(enorm[e3]);                       \
        if ((B) >= cnt)     { s0 = wid; w0 = ((B) == cnt)     ? di2 : 0.f; }    \
        if ((B) + 1 >= cnt) { s1 = wid; w1 = ((B) + 1 == cnt) ? di2 : 0.f; }    \
        if ((B) + 2 >= cnt) { s2 = wid; w2 = ((B) + 2 == cnt) ? di2 : 0.f; }    \
        if ((B) + 3 >= cnt) { s3 = wid; w3 = ((B) + 3 == cnt) ? di2 : 0.f; }    \
        SS = g0 ? s0 : (g1 ? s1 : (g2 ? s2 : s3));                              \
        WW = g0 ? w0 : (g1 ? w1 : (g2 ? w2 : w3));                              \
    }

#define STEP_ACC(WW, V)                                                         \
    acc[0] += (WW) * __uint_as_float((V).x << 16);                              \
    acc[1] += (WW) * __uint_as_float((V).x & 0xffff0000u);                      \
    acc[2] += (WW) * __uint_as_float((V).y << 16);                              \
    acc[3] += (WW) * __uint_as_float((V).y & 0xffff0000u);                      \
    acc[4] += (WW) * __uint_as_float((V).z << 16);                              \
    acc[5] += (WW) * __uint_as_float((V).z & 0xffff0000u);                      \
    acc[6] += (WW) * __uint_as_float((V).w << 16);                              \
    acc[7] += (WW) * __uint_as_float((V).w & 0xffff0000u);

    // main loop: 4 steps (16 edges) per iter, 4 gather instrs in flight
    while (base + 16 <= items) {
        int   ss[4];
        float ws[4];
        uint4 vs[4];
        STEP_META(base + 0,  ss[0], ws[0])
        STEP_META(base + 4,  ss[1], ws[1])
        STEP_META(base + 8,  ss[2], ws[2])
        STEP_META(base + 12, ss[3], ws[3])
#pragma unroll
        for (int s = 0; s < 4; ++s)
            vs[s] = *(const uint4*)(hb + (size_t)ss[s] * 128 + (q << 3));
#pragma unroll
        for (int s = 0; s < 4; ++s) { STEP_ACC(ws[s], vs[s]) }
        base += 16;
    }
    // epilogue: one masked step at a time
    while (base < items) {
        int ssel; float wsel;
        STEP_META(base, ssel, wsel)
        uint4 v = *(const uint4*)(hb + (size_t)ssel * 128 + (q << 3));
        STEP_ACC(wsel, v)
        base += 4;
    }
#undef STEP_META
#undef STEP_ACC

    // sum the 4 groups' partials -> every lane holds slice q totals
#pragma unroll
    for (int j = 0; j < 8; ++j) {
        acc[j] += __shfl_xor(acc[j], 32, 64);
        acc[j] += __shfl_xor(acc[j], 16, 64);
    }

    // bias + relu (slice q -> feats q*8..q*8+7)
    float4 b0 = *(const float4*)(bias + (q << 3));
    float4 b1v = *(const float4*)(bias + (q << 3) + 4);
    acc[0] = fmaxf(acc[0] + b0.x, 0.f);  acc[1] = fmaxf(acc[1] + b0.y, 0.f);
    acc[2] = fmaxf(acc[2] + b0.z, 0.f);  acc[3] = fmaxf(acc[3] + b0.w, 0.f);
    acc[4] = fmaxf(acc[4] + b1v.x, 0.f); acc[5] = fmaxf(acc[5] + b1v.y, 0.f);
    acc[6] = fmaxf(acc[6] + b1v.z, 0.f); acc[7] = fmaxf(acc[7] + b1v.w, 0.f);

    if (MODE == 0) {
        if (lane < 16) {
            uint4 ov;
            ov.x = f2bf(acc[0]) | ((unsigned)f2bf(acc[1]) << 16);
            ov.y = f2bf(acc[2]) | ((unsigned)f2bf(acc[3]) << 16);
            ov.z = f2bf(acc[4]) | ((unsigned)f2bf(acc[5]) << 16);
            ov.w = f2bf(acc[6]) | ((unsigned)f2bf(acc[7]) << 16);
            *(uint4*)((unsigned short*)out + (size_t)wid * 128 + (q << 3)) = ov;
        }
    } else {
        float r[NC];
#pragma unroll
        for (int c = 0; c < NC; ++c) r[c] = 0.f;
#pragma unroll
        for (int j = 0; j < 8; ++j) {
            float a = acc[j];
            const float* wrow = Wc + ((q << 3) + j) * NC;
#pragma unroll
            for (int c = 0; c < NC; ++c) r[c] += a * wrow[c];
        }
#pragma unroll
        for (int off = 8; off; off >>= 1)
#pragma unroll
            for (int c = 0; c < NC; ++c) r[c] += __shfl_xor(r[c], off, 64);
        if (lane < NC) out[(size_t)wid * NC + lane] = r[lane] + bc[lane];
    }
}

extern "C" void kernel_launch(void* const* d_in, const int* in_sizes, int n_in,
                              void* d_out, int out_size, void* d_ws, size_t ws_size,
                              hipStream_t stream) {
    const float* x   = (const float*)d_in[0];
    const int*   ei  = (const int*)d_in[1];
    const float* ew  = (const float*)d_in[2];
    const float* W1  = (const float*)d_in[3];
    const float* b1  = (const float*)d_in[4];
    const float* W2  = (const float*)d_in[5];
    const float* b2  = (const float*)d_in[6];
    const float* Wc  = (const float*)d_in[7];
    const float* bc  = (const float*)d_in[8];
    float*       out = (float*)d_out;

    const int* src = ei;
    const int* dst = ei + N_EDGES;

    size_t off = 0;
    auto carve = [&](size_t bytes) {
        void* p = (char*)d_ws + off;
        off += (bytes + 255) & ~(size_t)255;
        return p;
    };
    unsigned short* hb  = (unsigned short*)carve((size_t)N_NODES * 128 * 2);
    unsigned short* hb1 = (unsigned short*)carve((size_t)N_NODES * 128 * 2);
    unsigned short* wt1 = (unsigned short*)carve(128 * 128 * 2);
    unsigned short* wt2 = (unsigned short*)carve(128 * 128 * 2);
    float* dinv   = (float*)carve((size_t)N_NODES * 4);
    int*   cnt    = (int*)carve((size_t)N_NODES * 4);
    int*   rowptr = (int*)carve((size_t)(N_NODES + 1) * 4);
    int*   bsum   = (int*)carve(256 * 4);
    int*   ord    = (int*)carve((size_t)N_EDGES * 4);
    int*   esrc   = (int*)carve((size_t)N_EDGES * 4);
    float* ew2    = (float*)carve((size_t)N_EDGES * 4);
    float* enorm  = (float*)carve((size_t)N_EDGES * 4);
    (void)ws_size; (void)n_in; (void)in_sizes; (void)out_size;

    int nb = (N_NODES + 255) / 256;
    int eb = (N_EDGES + 255) / 256;

    k_zero<<<(N_NODES / 4 + 255) / 256, 256, 0, stream>>>((int4*)cnt, N_NODES / 4);
    k_prep<<<128 + (N_EDGES / 4 + 255) / 256, 256, 0, stream>>>(
        W1, W2, wt1, wt2, (const int4*)dst, cnt, (int4*)ord);
    k_scan1<<<nb, 256, 0, stream>>>(cnt, rowptr, bsum, N_NODES);
    k_scan2<<<1, 256, 0, stream>>>(bsum, nb);
    k_scan3<<<nb, 256, 0, stream>>>(rowptr, bsum, N_NODES);
    k_sg<<<GB + eb, 256, 0, stream>>>(x, wt1, hb, N_NODES,
                                      src, dst, ew, ord, rowptr, esrc, ew2);
    k_deg<<<nb, 256, 0, stream>>>(rowptr, ew2, dinv);
    k_norm<<<nb, 256, 0, stream>>>(rowptr, esrc, ew2, dinv, enorm);

    k_agg<0><<<(N_NODES + 3) / 4, 256, 0, stream>>>(hb, rowptr, esrc,
                                                    enorm, dinv, b1, Wc, bc, (float*)hb1);
    k_gemm_mfma<<<GB, 256, 0, stream>>>(hb1, wt2, hb, N_NODES);
    k_agg<1><<<(N_NODES + 3) / 4, 256, 0, stream>>>(hb, rowptr, esrc,
                                                    enorm, dinv, b2, Wc, bc, out);
}

// Round 10
// 194.382 us; speedup vs baseline: 1.0076x; 1.0076x over previous
//
#include <hip/hip_runtime.h>
#include <hip/hip_bf16.h>

#define N_NODES 50000
#define N_EDGES 600000
#define NC 10
#define GB ((N_NODES + 63) / 64)

typedef __attribute__((ext_vector_type(8))) __bf16 bf16x8;
typedef __attribute__((ext_vector_type(8))) unsigned short u16x8;
typedef __attribute__((ext_vector_type(4))) float f32x4;

__device__ __forceinline__ unsigned short f2bf(float f) {
    unsigned u = __float_as_uint(f);
    u += 0x7fff + ((u >> 16) & 1);           // round-to-nearest-even
    return (unsigned short)(u >> 16);
}
__device__ __forceinline__ int rfl(int x) { return __builtin_amdgcn_readfirstlane(x); }

// ---------------- zero helper ----------------
__global__ void k_zero(int4* __restrict__ p, int n4) {
    int i = blockIdx.x * blockDim.x + threadIdx.x;
    if (i < n4) p[i] = make_int4(0, 0, 0, 0);
}

// ---------------- prep: W transposes + edge count (fused, independent) ------
__global__ void k_prep(const float* __restrict__ W1, const float* __restrict__ W2,
                       unsigned short* __restrict__ wt1, unsigned short* __restrict__ wt2,
                       const int4* __restrict__ dst4, int* __restrict__ cnt,
                       int4* __restrict__ ord4) {
    int b = blockIdx.x;
    if (b < 128) {
        const float* W = (b < 64) ? W1 : W2;
        unsigned short* Wt = (b < 64) ? wt1 : wt2;
        int i = (b & 63) * 256 + threadIdx.x;    // 0..16383
        int n = i >> 7, k = i & 127;
        Wt[n * 128 + k] = f2bf(W[k * 128 + n]);
    } else {
        int i = (b - 128) * 256 + threadIdx.x;
        if (i < N_EDGES / 4) {
            int4 d = dst4[i];
            int4 o;
            o.x = atomicAdd(&cnt[d.x], 1);
            o.y = atomicAdd(&cnt[d.y], 1);
            o.z = atomicAdd(&cnt[d.z], 1);
            o.w = atomicAdd(&cnt[d.w], 1);
            ord4[i] = o;
        }
    }
}

// ---------------- dual exclusive scan (exact + padded) ----------------
// padded row length = ((cnt+1)+3) & ~3  (edges + self-loop, padded to mult 4)
__global__ void k_scan1(const int* __restrict__ cnt, int* __restrict__ rowptr,
                        int* __restrict__ prowptr, int2* __restrict__ bsum, int n) {
    __shared__ int sa[256], sb[256];
    int t = threadIdx.x;
    int i = blockIdx.x * 256 + t;
    int v  = (i < n) ? cnt[i] : 0;
    int pv = (i < n) ? ((v + 4) & ~3) : 0;
    sa[t] = v; sb[t] = pv;
    __syncthreads();
    for (int off = 1; off < 256; off <<= 1) {
        int x = 0, y = 0;
        if (t >= off) { x = sa[t - off]; y = sb[t - off]; }
        __syncthreads();
        sa[t] += x; sb[t] += y;
        __syncthreads();
    }
    if (i < n) { rowptr[i] = sa[t] - v; prowptr[i] = sb[t] - pv; }
    if (t == 255) bsum[blockIdx.x] = make_int2(sa[255], sb[255]);
}

__global__ void k_scan2(int2* __restrict__ bsum, int nb) {
    __shared__ int sa[256], sb[256];
    int t = threadIdx.x;
    int2 v = (t < nb) ? bsum[t] : make_int2(0, 0);
    sa[t] = v.x; sb[t] = v.y;
    __syncthreads();
    for (int off = 1; off < 256; off <<= 1) {
        int x = 0, y = 0;
        if (t >= off) { x = sa[t - off]; y = sb[t - off]; }
        __syncthreads();
        sa[t] += x; sb[t] += y;
        __syncthreads();
    }
    if (t < nb) bsum[t] = make_int2(sa[t] - v.x, sb[t] - v.y);
}

__global__ void k_scan3(int* __restrict__ rowptr, int* __restrict__ prowptr,
                        const int2* __restrict__ bsum, const int* __restrict__ cnt, int n) {
    int t = threadIdx.x;
    int i = blockIdx.x * 256 + t;
    if (i < n) {
        int2 b = bsum[blockIdx.x];
        rowptr[i]  += b.x;
        prowptr[i] += b.y;
        if (i == n - 1) {
            rowptr[n]  = N_EDGES;
            prowptr[n] = prowptr[i] + ((cnt[i] + 4) & ~3);
        }
    }
}

// ---------------- shared GEMM body (MFMA, bf16) ----------------
template <int FP32IN>
__device__ __forceinline__ void gemm_body(unsigned short* Al, unsigned short* Bl,
                                          const void* __restrict__ Xin,
                                          const unsigned short* __restrict__ Wt,
                                          unsigned short* __restrict__ Yb,
                                          int M, int row0) {
    int t = threadIdx.x;
    for (int i = t; i < 2048; i += 256) {
        int r = i >> 4, q = i & 15;
        *(u16x8*)(Bl + r * 128 + ((q ^ (r & 7)) << 3)) =
            *(const u16x8*)(Wt + r * 128 + (q << 3));
    }
    for (int i = t; i < 1024; i += 256) {
        int r = i >> 4, q = i & 15;
        int gr = row0 + r;
        u16x8 v;
        if (FP32IN) {
            const float* X = (const float*)Xin;
            if (gr < M) {
                float4 f0 = *(const float4*)(X + (size_t)gr * 128 + (q << 3));
                float4 f1 = *(const float4*)(X + (size_t)gr * 128 + (q << 3) + 4);
                v[0] = f2bf(f0.x); v[1] = f2bf(f0.y); v[2] = f2bf(f0.z); v[3] = f2bf(f0.w);
                v[4] = f2bf(f1.x); v[5] = f2bf(f1.y); v[6] = f2bf(f1.z); v[7] = f2bf(f1.w);
            } else {
#pragma unroll
                for (int j = 0; j < 8; ++j) v[j] = 0;
            }
        } else {
            const unsigned short* X = (const unsigned short*)Xin;
            if (gr < M) {
                v = *(const u16x8*)(X + (size_t)gr * 128 + (q << 3));
            } else {
#pragma unroll
                for (int j = 0; j < 8; ++j) v[j] = 0;
            }
        }
        *(u16x8*)(Al + r * 128 + ((q ^ (r & 7)) << 3)) = v;
    }
    __syncthreads();

    int l  = t & 63;
    int w  = t >> 6;
    int ar = (w << 4) + (l & 15);
    int kq = l >> 4;

    bf16x8 af[4];
#pragma unroll
    for (int s = 0; s < 4; ++s) {
        int g = ((s << 2) + kq) ^ (l & 7);
        af[s] = *(const bf16x8*)(Al + ar * 128 + (g << 3));
    }

    f32x4 acc[8];
#pragma unroll
    for (int c = 0; c < 8; ++c)
#pragma unroll
        for (int j = 0; j < 4; ++j) acc[c][j] = 0.0f;

#pragma unroll
    for (int c = 0; c < 8; ++c) {
        int br = (c << 4) + (l & 15);
#pragma unroll
        for (int s = 0; s < 4; ++s) {
            int g = ((s << 2) + kq) ^ (l & 7);
            bf16x8 bf = *(const bf16x8*)(Bl + br * 128 + (g << 3));
            acc[c] = __builtin_amdgcn_mfma_f32_16x16x32_bf16(af[s], bf, acc[c], 0, 0, 0);
        }
    }

    int orow = row0 + (w << 4) + ((l >> 4) << 2);
    int ocol = l & 15;
#pragma unroll
    for (int c = 0; c < 8; ++c) {
#pragma unroll
        for (int j = 0; j < 4; ++j) {
            int r = orow + j;
            if (r < M) Yb[(size_t)r * 128 + (c << 4) + ocol] = f2bf(acc[c][j]);
        }
    }
}

// ---------------- fused: GEMM1 (fp32 x) + CSR scatter (independent) ---------
__global__ __launch_bounds__(256) void k_sg(const float* __restrict__ X,
                                            const unsigned short* __restrict__ Wt,
                                            unsigned short* __restrict__ Yb, int M,
                                            const int* __restrict__ src,
                                            const int* __restrict__ dst,
                                            const float* __restrict__ ew,
                                            const int* __restrict__ ord,
                                            const int* __restrict__ rowptr,
                                            int* __restrict__ esrc,
                                            float* __restrict__ ew2) {
    __shared__ unsigned short Al[64 * 128];
    __shared__ unsigned short Bl[128 * 128];
    if (blockIdx.x < GB) {
        gemm_body<1>(Al, Bl, X, Wt, Yb, M, blockIdx.x * 64);
    } else {
        int e = (blockIdx.x - GB) * 256 + threadIdx.x;
        if (e < N_EDGES) {
            int pos = rowptr[dst[e]] + ord[e];
            esrc[pos] = src[e];
            ew2[pos]  = ew[e];
        }
    }
}

// ---------------- standalone GEMM (bf16 in, layer 2) ----------------
__global__ __launch_bounds__(256) void k_gemm_mfma(const unsigned short* __restrict__ Xb,
                                                   const unsigned short* __restrict__ Wt,
                                                   unsigned short* __restrict__ Yb, int M) {
    __shared__ unsigned short Al[64 * 128];
    __shared__ unsigned short Bl[128 * 128];
    gemm_body<0>(Al, Bl, Xb, Wt, Yb, M, blockIdx.x * 64);
}

// ---------------- per-node degree -> dinv ----------------
__global__ void k_deg(const int* __restrict__ rowptr, const float* __restrict__ ew2,
                      float* __restrict__ dinv) {
    int i = blockIdx.x * blockDim.x + threadIdx.x;
    if (i >= N_NODES) return;
    int p1 = rowptr[i + 1];
    float s = 1.0f;
    for (int p = rowptr[i]; p < p1; ++p) s += ew2[p];
    dinv[i] = rsqrtf(s);
}

// ---------------- build padded (src, norm) edge array ----------------
// Per node: real edges, then self-loop (i, di^2), then (i, 0) pads to mult 4.
__global__ void k_norm(const int* __restrict__ rowptr, const int* __restrict__ prowptr,
                       const int* __restrict__ esrc, const float* __restrict__ ew2,
                       const float* __restrict__ dinv, int2* __restrict__ epad) {
    int i = blockIdx.x * blockDim.x + threadIdx.x;
    if (i >= N_NODES) return;
    int row  = rowptr[i];
    int cnt  = rowptr[i + 1] - row;
    int prow = prowptr[i];
    int plen = prowptr[i + 1] - prow;
    float di = dinv[i];
    int j = 0;
    for (; j < cnt; ++j) {
        int s = esrc[row + j];
        epad[prow + j] = make_int2(s, __float_as_int(dinv[s] * ew2[row + j] * di));
    }
    epad[prow + j] = make_int2(i, __float_as_int(di * di));
    for (++j; j < plen; ++j) epad[prow + j] = make_int2(i, 0);
}

// ---------------- aggregation: 4 edges per gather request ----------------
// Wave = 1 node. Lane group g (lane>>4) owns edge base+4s+g at step s; lane
// q (lane&15) holds 16B (8 bf16 feats) of that row -> one dwordx4 instr
// gathers 4 rows (1KB). Metadata: ONE int2 load per 16 edges + 2 bpermutes
// per step. No rfl/clamps in the loop (R9 lesson).
// MODE 0: out = relu(agg + bias) packed bf16; MODE 1: fused classifier.
template <int MODE>
__global__ __launch_bounds__(256) void k_agg(const unsigned short* __restrict__ hb,
                                             const int* __restrict__ prowptr,
                                             const int2* __restrict__ epad,
                                             const float* __restrict__ bias,
                                             const float* __restrict__ Wc,
                                             const float* __restrict__ bc,
                                             float* __restrict__ out) {
    int wid  = (blockIdx.x * blockDim.x + threadIdx.x) >> 6;
    int lane = threadIdx.x & 63;
    if (wid >= N_NODES) return;
    wid = rfl(wid);
    int pp  = rfl(prowptr[wid]);
    int len = rfl(prowptr[wid + 1]) - pp;    // multiple of 4, >= 4
    int g = lane >> 4;
    int q = lane & 15;

    float acc[8];
#pragma unroll
    for (int j = 0; j < 8; ++j) acc[j] = 0.f;

#define STEP_ACC(WW, V)                                                         \
    acc[0] += (WW) * __uint_as_float((V).x << 16);                              \
    acc[1] += (WW) * __uint_as_float((V).x & 0xffff0000u);                      \
    acc[2] += (WW) * __uint_as_float((V).y << 16);                              \
    acc[3] += (WW) * __uint_as_float((V).y & 0xffff0000u);                      \
    acc[4] += (WW) * __uint_as_float((V).z << 16);                              \
    acc[5] += (WW) * __uint_as_float((V).z & 0xffff0000u);                      \
    acc[6] += (WW) * __uint_as_float((V).w << 16);                              \
    acc[7] += (WW) * __uint_as_float((V).w & 0xffff0000u);

    int base = 0;
    while (base + 16 <= len) {
        int2 m = epad[pp + base + q];        // 16 entries, broadcast x4 groups
        int   sv[4]; float wv[4]; uint4 vv[4];
#pragma unroll
        for (int s = 0; s < 4; ++s) {
            int idx = ((s << 2) + g) << 2;   // byte index = src_lane*4
            sv[s] = __builtin_amdgcn_ds_bpermute(idx, m.x);
            wv[s] = __uint_as_float((unsigned)__builtin_amdgcn_ds_bpermute(idx, m.y));
        }
#pragma unroll
        for (int s = 0; s < 4; ++s)
            vv[s] = *(const uint4*)(hb + (size_t)sv[s] * 128 + (q << 3));
#pragma unroll
        for (int s = 0; s < 4; ++s) { STEP_ACC(wv[s], vv[s]) }
        base += 16;
    }
    if (base < len) {
        int2 m = epad[pp + base + q];        // may over-read pad slack (safe)
        int steps = (len - base) >> 2;       // 1..3
        int   sv[3]; float wv[3]; uint4 vv[3];
#pragma unroll
        for (int s = 0; s < 3; ++s) {
            int idx = ((s << 2) + g) << 2;
            sv[s] = __builtin_amdgcn_ds_bpermute(idx, m.x);
            wv[s] = __uint_as_float((unsigned)__builtin_amdgcn_ds_bpermute(idx, m.y));
        }
#pragma unroll
        for (int s = 0; s < 3; ++s)
            if (s < steps) vv[s] = *(const uint4*)(hb + (size_t)sv[s] * 128 + (q << 3));
#pragma unroll
        for (int s = 0; s < 3; ++s)
            if (s < steps) { STEP_ACC(wv[s], vv[s]) }
    }
#undef STEP_ACC

    // sum the 4 groups' partials -> every lane holds slice-q totals
#pragma unroll
    for (int j = 0; j < 8; ++j) {
        acc[j] += __shfl_xor(acc[j], 32, 64);
        acc[j] += __shfl_xor(acc[j], 16, 64);
    }

    float4 b0 = *(const float4*)(bias + (q << 3));
    float4 b1v = *(const float4*)(bias + (q << 3) + 4);
    acc[0] = fmaxf(acc[0] + b0.x, 0.f);  acc[1] = fmaxf(acc[1] + b0.y, 0.f);
    acc[2] = fmaxf(acc[2] + b0.z, 0.f);  acc[3] = fmaxf(acc[3] + b0.w, 0.f);
    acc[4] = fmaxf(acc[4] + b1v.x, 0.f); acc[5] = fmaxf(acc[5] + b1v.y, 0.f);
    acc[6] = fmaxf(acc[6] + b1v.z, 0.f); acc[7] = fmaxf(acc[7] + b1v.w, 0.f);

    if (MODE == 0) {
        if (lane < 16) {
            uint4 ov;
            ov.x = f2bf(acc[0]) | ((unsigned)f2bf(acc[1]) << 16);
            ov.y = f2bf(acc[2]) | ((unsigned)f2bf(acc[3]) << 16);
            ov.z = f2bf(acc[4]) | ((unsigned)f2bf(acc[5]) << 16);
            ov.w = f2bf(acc[6]) | ((unsigned)f2bf(acc[7]) << 16);
            *(uint4*)((unsigned short*)out + (size_t)wid * 128 + (q << 3)) = ov;
        }
    } else {
        float r[NC];
#pragma unroll
        for (int c = 0; c < NC; ++c) r[c] = 0.f;
#pragma unroll
        for (int j = 0; j < 8; ++j) {
            float a = acc[j];
            const float* wrow = Wc + ((q << 3) + j) * NC;
#pragma unroll
            for (int c = 0; c < NC; ++c) r[c] += a * wrow[c];
        }
#pragma unroll
        for (int off = 8; off; off >>= 1)
#pragma unroll
            for (int c = 0; c < NC; ++c) r[c] += __shfl_xor(r[c], off, 64);
        if (lane < NC) out[(size_t)wid * NC + lane] = r[lane] + bc[lane];
    }
}

extern "C" void kernel_launch(void* const* d_in, const int* in_sizes, int n_in,
                              void* d_out, int out_size, void* d_ws, size_t ws_size,
                              hipStream_t stream) {
    const float* x   = (const float*)d_in[0];
    const int*   ei  = (const int*)d_in[1];
    const float* ew  = (const float*)d_in[2];
    const float* W1  = (const float*)d_in[3];
    const float* b1  = (const float*)d_in[4];
    const float* W2  = (const float*)d_in[5];
    const float* b2  = (const float*)d_in[6];
    const float* Wc  = (const float*)d_in[7];
    const float* bc  = (const float*)d_in[8];
    float*       out = (float*)d_out;

    const int* src = ei;
    const int* dst = ei + N_EDGES;

    size_t off = 0;
    auto carve = [&](size_t bytes) {
        void* p = (char*)d_ws + off;
        off += (bytes + 255) & ~(size_t)255;
        return p;
    };
    unsigned short* hb  = (unsigned short*)carve((size_t)N_NODES * 128 * 2);
    unsigned short* hb1 = (unsigned short*)carve((size_t)N_NODES * 128 * 2);
    unsigned short* wt1 = (unsigned short*)carve(128 * 128 * 2);
    unsigned short* wt2 = (unsigned short*)carve(128 * 128 * 2);
    float* dinv    = (float*)carve((size_t)N_NODES * 4);
    int*   cnt     = (int*)carve((size_t)N_NODES * 4);
    int*   rowptr  = (int*)carve((size_t)(N_NODES + 1) * 4);
    int*   prowptr = (int*)carve((size_t)(N_NODES + 1) * 4);
    int2*  bsum    = (int2*)carve(256 * 8);
    int*   ord     = (int*)carve((size_t)N_EDGES * 4);
    int*   esrc    = (int*)carve((size_t)N_EDGES * 4);
    float* ew2     = (float*)carve((size_t)N_EDGES * 4);
    int2*  epad    = (int2*)carve(((size_t)N_EDGES + 4 * N_NODES + 16) * 8);
    (void)ws_size; (void)n_in; (void)in_sizes; (void)out_size;

    int nb = (N_NODES + 255) / 256;
    int eb = (N_EDGES + 255) / 256;

    k_zero<<<(N_NODES / 4 + 255) / 256, 256, 0, stream>>>((int4*)cnt, N_NODES / 4);
    k_prep<<<128 + (N_EDGES / 4 + 255) / 256, 256, 0, stream>>>(
        W1, W2, wt1, wt2, (const int4*)dst, cnt, (int4*)ord);
    k_scan1<<<nb, 256, 0, stream>>>(cnt, rowptr, prowptr, bsum, N_NODES);
    k_scan2<<<1, 256, 0, stream>>>(bsum, nb);
    k_scan3<<<nb, 256, 0, stream>>>(rowptr, prowptr, bsum, cnt, N_NODES);
    k_sg<<<GB + eb, 256, 0, stream>>>(x, wt1, hb, N_NODES,
                                      src, dst, ew, ord, rowptr, esrc, ew2);
    k_deg<<<nb, 256, 0, stream>>>(rowptr, ew2, dinv);
    k_norm<<<nb, 256, 0, stream>>>(rowptr, prowptr, esrc, ew2, dinv, epad);

    k_agg<0><<<(N_NODES + 3) / 4, 256, 0, stream>>>(hb, prowptr, epad,
                                                    b1, Wc, bc, (float*)hb1);
    k_gemm_mfma<<<GB, 256, 0, stream>>>(hb1, wt2, hb, N_NODES);
    k_agg<1><<<(N_NODES + 3) / 4, 256, 0, stream>>>(hb, prowptr, epad,
                                                    b2, Wc, bc, out);
}

// Round 11
// 173.779 us; speedup vs baseline: 1.1271x; 1.1186x over previous
//
#include <hip/hip_runtime.h>
#include <hip/hip_bf16.h>

#define N_NODES 50000
#define N_EDGES 600000
#define NC 10
#define GB ((N_NODES + 63) / 64)

typedef __attribute__((ext_vector_type(8))) __bf16 bf16x8;
typedef __attribute__((ext_vector_type(8))) unsigned short u16x8;
typedef __attribute__((ext_vector_type(4))) float f32x4;

__device__ __forceinline__ unsigned short f2bf(float f) {
    unsigned u = __float_as_uint(f);
    u += 0x7fff + ((u >> 16) & 1);           // round-to-nearest-even
    return (unsigned short)(u >> 16);
}
__device__ __forceinline__ int rfl(int x) { return __builtin_amdgcn_readfirstlane(x); }
__device__ __forceinline__ float rflf(float x) {
    return __uint_as_float(__builtin_amdgcn_readfirstlane(__float_as_uint(x)));
}

// ---------------- zero helper ----------------
__global__ void k_zero(int4* __restrict__ p, int n4) {
    int i = blockIdx.x * blockDim.x + threadIdx.x;
    if (i < n4) p[i] = make_int4(0, 0, 0, 0);
}

// ---------------- prep: W transposes + edge count (fused, independent) ------
__global__ void k_prep(const float* __restrict__ W1, const float* __restrict__ W2,
                       unsigned short* __restrict__ wt1, unsigned short* __restrict__ wt2,
                       const int4* __restrict__ dst4, int* __restrict__ cnt,
                       int4* __restrict__ ord4) {
    int b = blockIdx.x;
    if (b < 128) {
        const float* W = (b < 64) ? W1 : W2;
        unsigned short* Wt = (b < 64) ? wt1 : wt2;
        int i = (b & 63) * 256 + threadIdx.x;    // 0..16383
        int n = i >> 7, k = i & 127;
        Wt[n * 128 + k] = f2bf(W[k * 128 + n]);
    } else {
        int i = (b - 128) * 256 + threadIdx.x;
        if (i < N_EDGES / 4) {
            int4 d = dst4[i];
            int4 o;
            o.x = atomicAdd(&cnt[d.x], 1);
            o.y = atomicAdd(&cnt[d.y], 1);
            o.z = atomicAdd(&cnt[d.z], 1);
            o.w = atomicAdd(&cnt[d.w], 1);
            ord4[i] = o;
        }
    }
}

// ---------------- exclusive scan (3 kernels) ----------------
__global__ void k_scan1(const int* __restrict__ cnt, int* __restrict__ rowptr,
                        int* __restrict__ bsum, int n) {
    __shared__ int sh[256];
    int t = threadIdx.x;
    int i = blockIdx.x * 256 + t;
    int v = (i < n) ? cnt[i] : 0;
    sh[t] = v;
    __syncthreads();
    for (int off = 1; off < 256; off <<= 1) {
        int x = 0;
        if (t >= off) x = sh[t - off];
        __syncthreads();
        sh[t] += x;
        __syncthreads();
    }
    if (i < n) rowptr[i] = sh[t] - v;
    if (t == 255) bsum[blockIdx.x] = sh[255];
}

__global__ void k_scan2(int* __restrict__ bsum, int nb) {
    __shared__ int sh[256];
    int t = threadIdx.x;
    int v = (t < nb) ? bsum[t] : 0;
    sh[t] = v;
    __syncthreads();
    for (int off = 1; off < 256; off <<= 1) {
        int x = 0;
        if (t >= off) x = sh[t - off];
        __syncthreads();
        sh[t] += x;
        __syncthreads();
    }
    if (t < nb) bsum[t] = sh[t] - v;
}

__global__ void k_scan3(int* __restrict__ rowptr, const int* __restrict__ bsum, int n) {
    int t = threadIdx.x;
    int i = blockIdx.x * 256 + t;
    if (i < n) rowptr[i] += bsum[blockIdx.x];
    if (blockIdx.x == 0 && t == 0) rowptr[n] = N_EDGES;
}

// ---------------- shared GEMM body (MFMA, bf16) ----------------
template <int FP32IN>
__device__ __forceinline__ void gemm_body(unsigned short* Al, unsigned short* Bl,
                                          const void* __restrict__ Xin,
                                          const unsigned short* __restrict__ Wt,
                                          unsigned short* __restrict__ Yb,
                                          int M, int row0) {
    int t = threadIdx.x;
    for (int i = t; i < 2048; i += 256) {
        int r = i >> 4, q = i & 15;
        *(u16x8*)(Bl + r * 128 + ((q ^ (r & 7)) << 3)) =
            *(const u16x8*)(Wt + r * 128 + (q << 3));
    }
    for (int i = t; i < 1024; i += 256) {
        int r = i >> 4, q = i & 15;
        int gr = row0 + r;
        u16x8 v;
        if (FP32IN) {
            const float* X = (const float*)Xin;
            if (gr < M) {
                float4 f0 = *(const float4*)(X + (size_t)gr * 128 + (q << 3));
                float4 f1 = *(const float4*)(X + (size_t)gr * 128 + (q << 3) + 4);
                v[0] = f2bf(f0.x); v[1] = f2bf(f0.y); v[2] = f2bf(f0.z); v[3] = f2bf(f0.w);
                v[4] = f2bf(f1.x); v[5] = f2bf(f1.y); v[6] = f2bf(f1.z); v[7] = f2bf(f1.w);
            } else {
#pragma unroll
                for (int j = 0; j < 8; ++j) v[j] = 0;
            }
        } else {
            const unsigned short* X = (const unsigned short*)Xin;
            if (gr < M) {
                v = *(const u16x8*)(X + (size_t)gr * 128 + (q << 3));
            } else {
#pragma unroll
                for (int j = 0; j < 8; ++j) v[j] = 0;
            }
        }
        *(u16x8*)(Al + r * 128 + ((q ^ (r & 7)) << 3)) = v;
    }
    __syncthreads();

    int l  = t & 63;
    int w  = t >> 6;
    int ar = (w << 4) + (l & 15);
    int kq = l >> 4;

    bf16x8 af[4];
#pragma unroll
    for (int s = 0; s < 4; ++s) {
        int g = ((s << 2) + kq) ^ (l & 7);
        af[s] = *(const bf16x8*)(Al + ar * 128 + (g << 3));
    }

    f32x4 acc[8];
#pragma unroll
    for (int c = 0; c < 8; ++c)
#pragma unroll
        for (int j = 0; j < 4; ++j) acc[c][j] = 0.0f;

#pragma unroll
    for (int c = 0; c < 8; ++c) {
        int br = (c << 4) + (l & 15);
#pragma unroll
        for (int s = 0; s < 4; ++s) {
            int g = ((s << 2) + kq) ^ (l & 7);
            bf16x8 bf = *(const bf16x8*)(Bl + br * 128 + (g << 3));
            acc[c] = __builtin_amdgcn_mfma_f32_16x16x32_bf16(af[s], bf, acc[c], 0, 0, 0);
        }
    }

    int orow = row0 + (w << 4) + ((l >> 4) << 2);
    int ocol = l & 15;
#pragma unroll
    for (int c = 0; c < 8; ++c) {
#pragma unroll
        for (int j = 0; j < 4; ++j) {
            int r = orow + j;
            if (r < M) Yb[(size_t)r * 128 + (c << 4) + ocol] = f2bf(acc[c][j]);
        }
    }
}

// ---------------- fused: GEMM1 (fp32 x) + CSR scatter (independent) ---------
__global__ __launch_bounds__(256) void k_sg(const float* __restrict__ X,
                                            const unsigned short* __restrict__ Wt,
                                            unsigned short* __restrict__ Yb, int M,
                                            const int* __restrict__ src,
                                            const int* __restrict__ dst,
                                            const float* __restrict__ ew,
                                            const int* __restrict__ ord,
                                            const int* __restrict__ rowptr,
                                            int* __restrict__ esrc,
                                            float* __restrict__ ew2) {
    __shared__ unsigned short Al[64 * 128];
    __shared__ unsigned short Bl[128 * 128];
    if (blockIdx.x < GB) {
        gemm_body<1>(Al, Bl, X, Wt, Yb, M, blockIdx.x * 64);
    } else {
        int e = (blockIdx.x - GB) * 256 + threadIdx.x;
        if (e < N_EDGES) {
            int pos = rowptr[dst[e]] + ord[e];
            esrc[pos] = src[e];
            ew2[pos]  = ew[e];
        }
    }
}

// ---------------- per-node degree -> dinv ----------------
__global__ void k_deg(const int* __restrict__ rowptr, const float* __restrict__ ew2,
                      float* __restrict__ dinv) {
    int i = blockIdx.x * blockDim.x + threadIdx.x;
    if (i >= N_NODES) return;
    int p1 = rowptr[i + 1];
    float s = 1.0f;
    for (int p = rowptr[i]; p < p1; ++p) s += ew2[p];
    dinv[i] = rsqrtf(s);
}

// ---------------- per-node edge norms ----------------
__global__ void k_norm(const int* __restrict__ rowptr, const int* __restrict__ esrc,
                       const float* __restrict__ ew2, const float* __restrict__ dinv,
                       float* __restrict__ enorm) {
    int i = blockIdx.x * blockDim.x + threadIdx.x;
    if (i >= N_NODES) return;
    float di = dinv[i];
    int p  = rowptr[i];
    int p1 = rowptr[i + 1];
    for (; p + 4 <= p1; p += 4) {
        int s0 = esrc[p], s1 = esrc[p+1], s2 = esrc[p+2], s3 = esrc[p+3];
        float d0 = dinv[s0], d1 = dinv[s1], d2 = dinv[s2], d3 = dinv[s3];
        enorm[p]   = d0 * ew2[p]   * di;
        enorm[p+1] = d1 * ew2[p+1] * di;
        enorm[p+2] = d2 * ew2[p+2] * di;
        enorm[p+3] = d3 * ew2[p+3] * di;
    }
    for (; p < p1; ++p) enorm[p] = dinv[esrc[p]] * ew2[p] * di;
}

// ---------------- R8-style per-node aggregation body (proven 41.5us form) ---
__device__ __forceinline__ float2 agg_row(const unsigned* __restrict__ hb,
                                          const int* __restrict__ rowptr,
                                          const int* __restrict__ esrc,
                                          const float* __restrict__ enorm,
                                          const float* __restrict__ dinv,
                                          int node, int lane) {
    int p  = rfl(rowptr[node]);
    int p1 = rfl(rowptr[node + 1]);
    float di  = dinv[node];
    float di2 = di * di;
    unsigned sv = hb[(size_t)node * 64 + lane];
    float2 acc;
    acc.x = __uint_as_float(sv << 16) * di2;
    acc.y = __uint_as_float(sv & 0xffff0000u) * di2;

    while (p + 16 <= p1) {
        int s[16]; float w[16]; unsigned v[16];
#pragma unroll
        for (int i = 0; i < 16; ++i) {
            s[i] = rfl(esrc[p + i]);
            w[i] = rflf(enorm[p + i]);
        }
#pragma unroll
        for (int i = 0; i < 16; ++i) v[i] = hb[(size_t)s[i] * 64 + lane];
#pragma unroll
        for (int i = 0; i < 16; ++i) {
            acc.x += w[i] * __uint_as_float(v[i] << 16);
            acc.y += w[i] * __uint_as_float(v[i] & 0xffff0000u);
        }
        p += 16;
    }
    while (p + 4 <= p1) {
        int s[4]; float w[4]; unsigned v[4];
#pragma unroll
        for (int i = 0; i < 4; ++i) {
            s[i] = rfl(esrc[p + i]);
            w[i] = rflf(enorm[p + i]);
        }
#pragma unroll
        for (int i = 0; i < 4; ++i) v[i] = hb[(size_t)s[i] * 64 + lane];
#pragma unroll
        for (int i = 0; i < 4; ++i) {
            acc.x += w[i] * __uint_as_float(v[i] << 16);
            acc.y += w[i] * __uint_as_float(v[i] & 0xffff0000u);
        }
        p += 4;
    }
    for (; p < p1; ++p) {
        int s = rfl(esrc[p]);
        float w = rflf(enorm[p]);
        unsigned v = hb[(size_t)s * 64 + lane];
        acc.x += w * __uint_as_float(v << 16);
        acc.y += w * __uint_as_float(v & 0xffff0000u);
    }
    return acc;
}

// ---------------- fused agg1 + GEMM2 ----------------
// Block = 64 nodes. Phase 1: each of 4 waves aggregates 16 nodes (R8 pattern),
// relu+bias, writes bf16 rows into LDS (GEMM-swizzled). Phase 2: MFMA GEMM
// 64x128x128 with A from LDS, B (wt2) from global (L2-hot, 32KB shared).
__global__ __launch_bounds__(256) void k_ag(const unsigned* __restrict__ hb,
                                            const int* __restrict__ rowptr,
                                            const int* __restrict__ esrc,
                                            const float* __restrict__ enorm,
                                            const float* __restrict__ dinv,
                                            const float* __restrict__ bias,
                                            const unsigned short* __restrict__ Wt,
                                            unsigned short* __restrict__ Yb, int M) {
    __shared__ unsigned short Al[64 * 128];   // 16 KB
    int t = threadIdx.x;
    int l = t & 63;
    int w = t >> 6;
    int row0 = blockIdx.x * 64;

    // phase 1: aggregate 16 rows per wave
    for (int nd = 0; nd < 16; ++nd) {
        int r = (w << 4) + nd;           // local row
        int node = row0 + r;
        float2 acc = make_float2(0.f, 0.f);
        if (node < M) {
            acc = agg_row(hb, rowptr, esrc, enorm, dinv, node, l);
            float2 bv = ((const float2*)bias)[l];
            acc.x = fmaxf(acc.x + bv.x, 0.f);
            acc.y = fmaxf(acc.y + bv.y, 0.f);
        }
        unsigned val = f2bf(acc.x) | ((unsigned)f2bf(acc.y) << 16);
        int q = l >> 2;                  // 16B granule 0..15
        *(unsigned*)(Al + r * 128 + ((q ^ (r & 7)) << 3) + ((l & 3) << 1)) = val;
    }
    __syncthreads();

    // phase 2: GEMM tile
    int ar = (w << 4) + (l & 15);
    int kq = l >> 4;
    bf16x8 af[4];
#pragma unroll
    for (int s = 0; s < 4; ++s) {
        int g = ((s << 2) + kq) ^ (ar & 7);
        af[s] = *(const bf16x8*)(Al + ar * 128 + (g << 3));
    }

    f32x4 acc2[8];
#pragma unroll
    for (int c = 0; c < 8; ++c)
#pragma unroll
        for (int j = 0; j < 4; ++j) acc2[c][j] = 0.0f;

#pragma unroll
    for (int c = 0; c < 8; ++c) {
        int br = (c << 4) + (l & 15);
#pragma unroll
        for (int s = 0; s < 4; ++s) {
            bf16x8 bf = *(const bf16x8*)(Wt + br * 128 + (((s << 2) + kq) << 3));
            acc2[c] = __builtin_amdgcn_mfma_f32_16x16x32_bf16(af[s], bf, acc2[c], 0, 0, 0);
        }
    }

    int orow = row0 + (w << 4) + ((l >> 4) << 2);
    int ocol = l & 15;
#pragma unroll
    for (int c = 0; c < 8; ++c) {
#pragma unroll
        for (int j = 0; j < 4; ++j) {
            int r = orow + j;
            if (r < M) Yb[(size_t)r * 128 + (c << 4) + ocol] = f2bf(acc2[c][j]);
        }
    }
}

// ---------------- agg2 + fused classifier (R8-proven form) ----------------
__global__ __launch_bounds__(256) void k_agg(const unsigned* __restrict__ hb,
                                             const int* __restrict__ rowptr,
                                             const int* __restrict__ esrc,
                                             const float* __restrict__ enorm,
                                             const float* __restrict__ dinv,
                                             const float* __restrict__ bias,
                                             const float* __restrict__ Wc,
                                             const float* __restrict__ bc,
                                             float* __restrict__ out) {
    int wid  = (blockIdx.x * blockDim.x + threadIdx.x) >> 6;
    int lane = threadIdx.x & 63;
    if (wid >= N_NODES) return;
    wid = rfl(wid);
    float2 acc = agg_row(hb, rowptr, esrc, enorm, dinv, wid, lane);
    float2 bv = ((const float2*)bias)[lane];
    acc.x = fmaxf(acc.x + bv.x, 0.f);
    acc.y = fmaxf(acc.y + bv.y, 0.f);

    int k0 = 2 * lane;
    float r[NC];
#pragma unroll
    for (int c = 0; c < NC; ++c)
        r[c] = acc.x * Wc[k0 * NC + c] + acc.y * Wc[(k0 + 1) * NC + c];
#pragma unroll
    for (int off = 32; off; off >>= 1)
#pragma unroll
        for (int c = 0; c < NC; ++c)
            r[c] += __shfl_xor(r[c], off, 64);
    if (lane < NC) out[(size_t)wid * NC + lane] = r[lane] + bc[lane];
}

extern "C" void kernel_launch(void* const* d_in, const int* in_sizes, int n_in,
                              void* d_out, int out_size, void* d_ws, size_t ws_size,
                              hipStream_t stream) {
    const float* x   = (const float*)d_in[0];
    const int*   ei  = (const int*)d_in[1];
    const float* ew  = (const float*)d_in[2];
    const float* W1  = (const float*)d_in[3];
    const float* b1  = (const float*)d_in[4];
    const float* W2  = (const float*)d_in[5];
    const float* b2  = (const float*)d_in[6];
    const float* Wc  = (const float*)d_in[7];
    const float* bc  = (const float*)d_in[8];
    float*       out = (float*)d_out;

    const int* src = ei;
    const int* dst = ei + N_EDGES;

    size_t off = 0;
    auto carve = [&](size_t bytes) {
        void* p = (char*)d_ws + off;
        off += (bytes + 255) & ~(size_t)255;
        return p;
    };
    unsigned short* hb  = (unsigned short*)carve((size_t)N_NODES * 128 * 2);
    unsigned short* hb2 = (unsigned short*)carve((size_t)N_NODES * 128 * 2);
    unsigned short* wt1 = (unsigned short*)carve(128 * 128 * 2);
    unsigned short* wt2 = (unsigned short*)carve(128 * 128 * 2);
    float* dinv   = (float*)carve((size_t)N_NODES * 4);
    int*   cnt    = (int*)carve((size_t)N_NODES * 4);
    int*   rowptr = (int*)carve((size_t)(N_NODES + 1) * 4);
    int*   bsum   = (int*)carve(256 * 4);
    int*   ord    = (int*)carve((size_t)N_EDGES * 4);
    int*   esrc   = (int*)carve((size_t)N_EDGES * 4);
    float* ew2    = (float*)carve((size_t)N_EDGES * 4);
    float* enorm  = (float*)carve((size_t)N_EDGES * 4);
    (void)ws_size; (void)n_in; (void)in_sizes; (void)out_size;

    int nb = (N_NODES + 255) / 256;
    int eb = (N_EDGES + 255) / 256;

    k_zero<<<(N_NODES / 4 + 255) / 256, 256, 0, stream>>>((int4*)cnt, N_NODES / 4);
    k_prep<<<128 + (N_EDGES / 4 + 255) / 256, 256, 0, stream>>>(
        W1, W2, wt1, wt2, (const int4*)dst, cnt, (int4*)ord);
    k_scan1<<<nb, 256, 0, stream>>>(cnt, rowptr, bsum, N_NODES);
    k_scan2<<<1, 256, 0, stream>>>(bsum, nb);
    k_scan3<<<nb, 256, 0, stream>>>(rowptr, bsum, N_NODES);
    k_sg<<<GB + eb, 256, 0, stream>>>(x, wt1, hb, N_NODES,
                                      src, dst, ew, ord, rowptr, esrc, ew2);
    k_deg<<<nb, 256, 0, stream>>>(rowptr, ew2, dinv);
    k_norm<<<nb, 256, 0, stream>>>(rowptr, esrc, ew2, dinv, enorm);

    // fused layer-1 aggregation + layer-2 GEMM
    k_ag<<<GB, 256, 0, stream>>>((const unsigned*)hb, rowptr, esrc, enorm, dinv,
                                 b1, wt2, hb2, N_NODES);
    // layer-2 aggregation + classifier
    k_agg<<<(N_NODES + 3) / 4, 256, 0, stream>>>((const unsigned*)hb2, rowptr, esrc,
                                                 enorm, dinv, b2, Wc, bc, out);
}

// Round 12
// 169.816 us; speedup vs baseline: 1.1534x; 1.0233x over previous
//
#include <hip/hip_runtime.h>
#include <hip/hip_bf16.h>

#define N_NODES 50000
#define N_EDGES 600000
#define NC 10
#define GB ((N_NODES + 63) / 64)
#define NSPLIT 40000                      // agg1 pipeline split (multiple of 64)
#define AGGB2 ((N_NODES - NSPLIT) / 4)    // 2500 agg blocks in k_gx
#define GEMA  (NSPLIT / 64)               // 625 gemm blocks in k_gx
#define GEMB  ((N_NODES - NSPLIT + 63) / 64 + 1)  // 157 tail tiles

typedef __attribute__((ext_vector_type(8))) __bf16 bf16x8;
typedef __attribute__((ext_vector_type(8))) unsigned short u16x8;
typedef __attribute__((ext_vector_type(4))) float f32x4;

__device__ __forceinline__ unsigned short f2bf(float f) {
    unsigned u = __float_as_uint(f);
    u += 0x7fff + ((u >> 16) & 1);           // round-to-nearest-even
    return (unsigned short)(u >> 16);
}
__device__ __forceinline__ int rfl(int x) { return __builtin_amdgcn_readfirstlane(x); }
__device__ __forceinline__ float rflf(float x) {
    return __uint_as_float(__builtin_amdgcn_readfirstlane(__float_as_uint(x)));
}

// ---------------- zero helper ----------------
__global__ void k_zero(int4* __restrict__ p, int n4) {
    int i = blockIdx.x * blockDim.x + threadIdx.x;
    if (i < n4) p[i] = make_int4(0, 0, 0, 0);
}

// ---------------- prep: W transposes + edge count (fused, independent) ------
__global__ void k_prep(const float* __restrict__ W1, const float* __restrict__ W2,
                       unsigned short* __restrict__ wt1, unsigned short* __restrict__ wt2,
                       const int4* __restrict__ dst4, int* __restrict__ cnt,
                       int4* __restrict__ ord4) {
    int b = blockIdx.x;
    if (b < 128) {
        const float* W = (b < 64) ? W1 : W2;
        unsigned short* Wt = (b < 64) ? wt1 : wt2;
        int i = (b & 63) * 256 + threadIdx.x;    // 0..16383
        int n = i >> 7, k = i & 127;
        Wt[n * 128 + k] = f2bf(W[k * 128 + n]);
    } else {
        int i = (b - 128) * 256 + threadIdx.x;
        if (i < N_EDGES / 4) {
            int4 d = dst4[i];
            int4 o;
            o.x = atomicAdd(&cnt[d.x], 1);
            o.y = atomicAdd(&cnt[d.y], 1);
            o.z = atomicAdd(&cnt[d.z], 1);
            o.w = atomicAdd(&cnt[d.w], 1);
            ord4[i] = o;
        }
    }
}

// ---------------- exclusive scan (2 kernels) ----------------
__global__ void k_scan1(const int* __restrict__ cnt, int* __restrict__ rowptr,
                        int* __restrict__ bsum, int n) {
    __shared__ int sh[256];
    int t = threadIdx.x;
    int i = blockIdx.x * 256 + t;
    int v = (i < n) ? cnt[i] : 0;
    sh[t] = v;
    __syncthreads();
    for (int off = 1; off < 256; off <<= 1) {
        int x = 0;
        if (t >= off) x = sh[t - off];
        __syncthreads();
        sh[t] += x;
        __syncthreads();
    }
    if (i < n) rowptr[i] = sh[t] - v;
    if (t == 255) bsum[blockIdx.x] = sh[255];
}

// each block redundantly scans bsum (nb<=256) and applies its own prefix
__global__ void k_scan23(int* __restrict__ rowptr, const int* __restrict__ bsum,
                         int nb, int n) {
    __shared__ int sh[256];
    __shared__ int ex[256];
    int t = threadIdx.x;
    int v = (t < nb) ? bsum[t] : 0;
    sh[t] = v;
    __syncthreads();
    for (int off = 1; off < 256; off <<= 1) {
        int x = 0;
        if (t >= off) x = sh[t - off];
        __syncthreads();
        sh[t] += x;
        __syncthreads();
    }
    ex[t] = sh[t] - v;
    __syncthreads();
    int i = blockIdx.x * 256 + t;
    if (i < n) rowptr[i] += ex[blockIdx.x];
    if (blockIdx.x == 0 && t == 0) rowptr[n] = N_EDGES;
}

// ---------------- shared GEMM body (MFMA, bf16, full staging) ----------------
template <int FP32IN>
__device__ __forceinline__ void gemm_body(unsigned short* Al, unsigned short* Bl,
                                          const void* __restrict__ Xin,
                                          const unsigned short* __restrict__ Wt,
                                          unsigned short* __restrict__ Yb,
                                          int M, int row0) {
    int t = threadIdx.x;
    for (int i = t; i < 2048; i += 256) {
        int r = i >> 4, q = i & 15;
        *(u16x8*)(Bl + r * 128 + ((q ^ (r & 7)) << 3)) =
            *(const u16x8*)(Wt + r * 128 + (q << 3));
    }
    for (int i = t; i < 1024; i += 256) {
        int r = i >> 4, q = i & 15;
        int gr = row0 + r;
        u16x8 v;
        if (FP32IN) {
            const float* X = (const float*)Xin;
            if (gr < M) {
                float4 f0 = *(const float4*)(X + (size_t)gr * 128 + (q << 3));
                float4 f1 = *(const float4*)(X + (size_t)gr * 128 + (q << 3) + 4);
                v[0] = f2bf(f0.x); v[1] = f2bf(f0.y); v[2] = f2bf(f0.z); v[3] = f2bf(f0.w);
                v[4] = f2bf(f1.x); v[5] = f2bf(f1.y); v[6] = f2bf(f1.z); v[7] = f2bf(f1.w);
            } else {
#pragma unroll
                for (int j = 0; j < 8; ++j) v[j] = 0;
            }
        } else {
            const unsigned short* X = (const unsigned short*)Xin;
            if (gr < M) {
                v = *(const u16x8*)(X + (size_t)gr * 128 + (q << 3));
            } else {
#pragma unroll
                for (int j = 0; j < 8; ++j) v[j] = 0;
            }
        }
        *(u16x8*)(Al + r * 128 + ((q ^ (r & 7)) << 3)) = v;
    }
    __syncthreads();

    int l  = t & 63;
    int w  = t >> 6;
    int ar = (w << 4) + (l & 15);
    int kq = l >> 4;

    bf16x8 af[4];
#pragma unroll
    for (int s = 0; s < 4; ++s) {
        int g = ((s << 2) + kq) ^ (l & 7);
        af[s] = *(const bf16x8*)(Al + ar * 128 + (g << 3));
    }

    f32x4 acc[8];
#pragma unroll
    for (int c = 0; c < 8; ++c)
#pragma unroll
        for (int j = 0; j < 4; ++j) acc[c][j] = 0.0f;

#pragma unroll
    for (int c = 0; c < 8; ++c) {
        int br = (c << 4) + (l & 15);
#pragma unroll
        for (int s = 0; s < 4; ++s) {
            int g = ((s << 2) + kq) ^ (l & 7);
            bf16x8 bf = *(const bf16x8*)(Bl + br * 128 + (g << 3));
            acc[c] = __builtin_amdgcn_mfma_f32_16x16x32_bf16(af[s], bf, acc[c], 0, 0, 0);
        }
    }

    int orow = row0 + (w << 4) + ((l >> 4) << 2);
    int ocol = l & 15;
#pragma unroll
    for (int c = 0; c < 8; ++c) {
#pragma unroll
        for (int j = 0; j < 4; ++j) {
            int r = orow + j;
            if (r < M) Yb[(size_t)r * 128 + (c << 4) + ocol] = f2bf(acc[c][j]);
        }
    }
}

// ---------------- lite GEMM: A staged in 16KB LDS, B straight from L2 -------
__device__ __forceinline__ void gemm_lite(unsigned short* Al,
                                          const unsigned short* __restrict__ Xb,
                                          const unsigned short* __restrict__ Wt,
                                          unsigned short* __restrict__ Yb,
                                          int M, int row0) {
    int t = threadIdx.x;
    for (int i = t; i < 1024; i += 256) {
        int r = i >> 4, q = i & 15;
        int gr = row0 + r;
        u16x8 v;
        if (gr < M) {
            v = *(const u16x8*)(Xb + (size_t)gr * 128 + (q << 3));
        } else {
#pragma unroll
            for (int j = 0; j < 8; ++j) v[j] = 0;
        }
        *(u16x8*)(Al + r * 128 + ((q ^ (r & 7)) << 3)) = v;
    }
    __syncthreads();

    int l  = t & 63;
    int w  = t >> 6;
    int ar = (w << 4) + (l & 15);
    int kq = l >> 4;

    bf16x8 af[4];
#pragma unroll
    for (int s = 0; s < 4; ++s) {
        int g = ((s << 2) + kq) ^ (l & 7);
        af[s] = *(const bf16x8*)(Al + ar * 128 + (g << 3));
    }

    f32x4 acc[8];
#pragma unroll
    for (int c = 0; c < 8; ++c)
#pragma unroll
        for (int j = 0; j < 4; ++j) acc[c][j] = 0.0f;

#pragma unroll
    for (int c = 0; c < 8; ++c) {
        int br = (c << 4) + (l & 15);
#pragma unroll
        for (int s = 0; s < 4; ++s) {
            bf16x8 bf = *(const bf16x8*)(Wt + br * 128 + (((s << 2) + kq) << 3));
            acc[c] = __builtin_amdgcn_mfma_f32_16x16x32_bf16(af[s], bf, acc[c], 0, 0, 0);
        }
    }

    int orow = row0 + (w << 4) + ((l >> 4) << 2);
    int ocol = l & 15;
#pragma unroll
    for (int c = 0; c < 8; ++c) {
#pragma unroll
        for (int j = 0; j < 4; ++j) {
            int r = orow + j;
            if (r < M) Yb[(size_t)r * 128 + (c << 4) + ocol] = f2bf(acc[c][j]);
        }
    }
}

// ---------------- fused: GEMM1 (fp32 x) + CSR scatter (independent) ---------
__global__ __launch_bounds__(256) void k_sg(const float* __restrict__ X,
                                            const unsigned short* __restrict__ Wt,
                                            unsigned short* __restrict__ Yb, int M,
                                            const int* __restrict__ src,
                                            const int* __restrict__ dst,
                                            const float* __restrict__ ew,
                                            const int* __restrict__ ord,
                                            const int* __restrict__ rowptr,
                                            int* __restrict__ esrc,
                                            float* __restrict__ ew2) {
    __shared__ unsigned short Al[64 * 128];
    __shared__ unsigned short Bl[128 * 128];
    if (blockIdx.x < GB) {
        gemm_body<1>(Al, Bl, X, Wt, Yb, M, blockIdx.x * 64);
    } else {
        int e = (blockIdx.x - GB) * 256 + threadIdx.x;
        if (e < N_EDGES) {
            int pos = rowptr[dst[e]] + ord[e];
            esrc[pos] = src[e];
            ew2[pos]  = ew[e];
        }
    }
}

// ---------------- per-node degree -> dinv ----------------
__global__ void k_deg(const int* __restrict__ rowptr, const float* __restrict__ ew2,
                      float* __restrict__ dinv) {
    int i = blockIdx.x * blockDim.x + threadIdx.x;
    if (i >= N_NODES) return;
    int p1 = rowptr[i + 1];
    float s = 1.0f;
    for (int p = rowptr[i]; p < p1; ++p) s += ew2[p];
    dinv[i] = rsqrtf(s);
}

// ---------------- per-node edge norms ----------------
__global__ void k_norm(const int* __restrict__ rowptr, const int* __restrict__ esrc,
                       const float* __restrict__ ew2, const float* __restrict__ dinv,
                       float* __restrict__ enorm) {
    int i = blockIdx.x * blockDim.x + threadIdx.x;
    if (i >= N_NODES) return;
    float di = dinv[i];
    int p  = rowptr[i];
    int p1 = rowptr[i + 1];
    for (; p + 4 <= p1; p += 4) {
        int s0 = esrc[p], s1 = esrc[p+1], s2 = esrc[p+2], s3 = esrc[p+3];
        float d0 = dinv[s0], d1 = dinv[s1], d2 = dinv[s2], d3 = dinv[s3];
        enorm[p]   = d0 * ew2[p]   * di;
        enorm[p+1] = d1 * ew2[p+1] * di;
        enorm[p+2] = d2 * ew2[p+2] * di;
        enorm[p+3] = d3 * ew2[p+3] * di;
    }
    for (; p < p1; ++p) enorm[p] = dinv[esrc[p]] * ew2[p] * di;
}

// ---------------- R8-proven per-node aggregation body ----------------
__device__ __forceinline__ float2 agg_row(const unsigned* __restrict__ hb,
                                          const int* __restrict__ rowptr,
                                          const int* __restrict__ esrc,
                                          const float* __restrict__ enorm,
                                          const float* __restrict__ dinv,
                                          int node, int lane) {
    int p  = rfl(rowptr[node]);
    int p1 = rfl(rowptr[node + 1]);
    float di  = dinv[node];
    float di2 = di * di;
    unsigned sv = hb[(size_t)node * 64 + lane];
    float2 acc;
    acc.x = __uint_as_float(sv << 16) * di2;
    acc.y = __uint_as_float(sv & 0xffff0000u) * di2;

    while (p + 16 <= p1) {
        int s[16]; float w[16]; unsigned v[16];
#pragma unroll
        for (int i = 0; i < 16; ++i) {
            s[i] = rfl(esrc[p + i]);
            w[i] = rflf(enorm[p + i]);
        }
#pragma unroll
        for (int i = 0; i < 16; ++i) v[i] = hb[(size_t)s[i] * 64 + lane];
#pragma unroll
        for (int i = 0; i < 16; ++i) {
            acc.x += w[i] * __uint_as_float(v[i] << 16);
            acc.y += w[i] * __uint_as_float(v[i] & 0xffff0000u);
        }
        p += 16;
    }
    while (p + 4 <= p1) {
        int s[4]; float w[4]; unsigned v[4];
#pragma unroll
        for (int i = 0; i < 4; ++i) {
            s[i] = rfl(esrc[p + i]);
            w[i] = rflf(enorm[p + i]);
        }
#pragma unroll
        for (int i = 0; i < 4; ++i) v[i] = hb[(size_t)s[i] * 64 + lane];
#pragma unroll
        for (int i = 0; i < 4; ++i) {
            acc.x += w[i] * __uint_as_float(v[i] << 16);
            acc.y += w[i] * __uint_as_float(v[i] & 0xffff0000u);
        }
        p += 4;
    }
    for (; p < p1; ++p) {
        int s = rfl(esrc[p]);
        float w = rflf(enorm[p]);
        unsigned v = hb[(size_t)s * 64 + lane];
        acc.x += w * __uint_as_float(v << 16);
        acc.y += w * __uint_as_float(v & 0xffff0000u);
    }
    return acc;
}

// ---------------- agg MODE0 (bf16 out) with node offset ----------------
__global__ __launch_bounds__(256) void k_agg0(const unsigned* __restrict__ hb,
                                              const int* __restrict__ rowptr,
                                              const int* __restrict__ esrc,
                                              const float* __restrict__ enorm,
                                              const float* __restrict__ dinv,
                                              const float* __restrict__ bias,
                                              unsigned* __restrict__ outb, int node0) {
    int wid  = node0 + ((blockIdx.x * blockDim.x + threadIdx.x) >> 6);
    int lane = threadIdx.x & 63;
    if (wid >= N_NODES) return;
    wid = rfl(wid);
    float2 acc = agg_row(hb, rowptr, esrc, enorm, dinv, wid, lane);
    float2 bv = ((const float2*)bias)[lane];
    acc.x = fmaxf(acc.x + bv.x, 0.f);
    acc.y = fmaxf(acc.y + bv.y, 0.f);
    outb[(size_t)wid * 64 + lane] = f2bf(acc.x) | ((unsigned)f2bf(acc.y) << 16);
}

// ---------------- k_gx: agg1 tail blocks + GEMM2 head blocks (specialized) --
__global__ __launch_bounds__(256) void k_gx(const unsigned* __restrict__ hb,
                                            const int* __restrict__ rowptr,
                                            const int* __restrict__ esrc,
                                            const float* __restrict__ enorm,
                                            const float* __restrict__ dinv,
                                            const float* __restrict__ bias,
                                            unsigned* __restrict__ zb,       // z (bf16) out
                                            const unsigned short* __restrict__ zread,
                                            const unsigned short* __restrict__ wt2,
                                            unsigned short* __restrict__ hb2) {
    __shared__ unsigned short Al[64 * 128];   // 16 KB (gemm blocks only)
    if (blockIdx.x < AGGB2) {
        int wid  = NSPLIT + ((blockIdx.x * blockDim.x + threadIdx.x) >> 6);
        int lane = threadIdx.x & 63;
        if (wid >= N_NODES) return;
        wid = rfl(wid);
        float2 acc = agg_row(hb, rowptr, esrc, enorm, dinv, wid, lane);
        float2 bv = ((const float2*)bias)[lane];
        acc.x = fmaxf(acc.x + bv.x, 0.f);
        acc.y = fmaxf(acc.y + bv.y, 0.f);
        zb[(size_t)wid * 64 + lane] = f2bf(acc.x) | ((unsigned)f2bf(acc.y) << 16);
    } else {
        int row0 = (blockIdx.x - AGGB2) * 64;      // rows [0, NSPLIT)
        gemm_lite(Al, zread, wt2, hb2, NSPLIT, row0);
    }
}

// ---------------- GEMM2 tail (rows [NSPLIT, N)) ----------------
__global__ __launch_bounds__(256) void k_gemm2b(const unsigned short* __restrict__ zread,
                                                const unsigned short* __restrict__ wt2,
                                                unsigned short* __restrict__ hb2) {
    __shared__ unsigned short Al[64 * 128];
    int row0 = NSPLIT + blockIdx.x * 64;
    gemm_lite(Al, zread, wt2, hb2, N_NODES, row0);
}

// ---------------- agg2 + fused classifier ----------------
__global__ __launch_bounds__(256) void k_agg1(const unsigned* __restrict__ hb,
                                              const int* __restrict__ rowptr,
                                              const int* __restrict__ esrc,
                                              const float* __restrict__ enorm,
                                              const float* __restrict__ dinv,
                                              const float* __restrict__ bias,
                                              const float* __restrict__ Wc,
                                              const float* __restrict__ bc,
                                              float* __restrict__ out) {
    int wid  = (blockIdx.x * blockDim.x + threadIdx.x) >> 6;
    int lane = threadIdx.x & 63;
    if (wid >= N_NODES) return;
    wid = rfl(wid);
    float2 acc = agg_row(hb, rowptr, esrc, enorm, dinv, wid, lane);
    float2 bv = ((const float2*)bias)[lane];
    acc.x = fmaxf(acc.x + bv.x, 0.f);
    acc.y = fmaxf(acc.y + bv.y, 0.f);

    int k0 = 2 * lane;
    float r[NC];
#pragma unroll
    for (int c = 0; c < NC; ++c)
        r[c] = acc.x * Wc[k0 * NC + c] + acc.y * Wc[(k0 + 1) * NC + c];
#pragma unroll
    for (int off = 32; off; off >>= 1)
#pragma unroll
        for (int c = 0; c < NC; ++c)
            r[c] += __shfl_xor(r[c], off, 64);
    if (lane < NC) out[(size_t)wid * NC + lane] = r[lane] + bc[lane];
}

extern "C" void kernel_launch(void* const* d_in, const int* in_sizes, int n_in,
                              void* d_out, int out_size, void* d_ws, size_t ws_size,
                              hipStream_t stream) {
    const float* x   = (const float*)d_in[0];
    const int*   ei  = (const int*)d_in[1];
    const float* ew  = (const float*)d_in[2];
    const float* W1  = (const float*)d_in[3];
    const float* b1  = (const float*)d_in[4];
    const float* W2  = (const float*)d_in[5];
    const float* b2  = (const float*)d_in[6];
    const float* Wc  = (const float*)d_in[7];
    const float* bc  = (const float*)d_in[8];
    float*       out = (float*)d_out;

    const int* src = ei;
    const int* dst = ei + N_EDGES;

    size_t off = 0;
    auto carve = [&](size_t bytes) {
        void* p = (char*)d_ws + off;
        off += (bytes + 255) & ~(size_t)255;
        return p;
    };
    unsigned short* hb  = (unsigned short*)carve((size_t)N_NODES * 128 * 2); // layer1 h
    unsigned short* zb  = (unsigned short*)carve((size_t)N_NODES * 128 * 2); // z = relu(agg1)
    unsigned short* hb2 = (unsigned short*)carve((size_t)N_NODES * 128 * 2); // gemm2 out
    unsigned short* wt1 = (unsigned short*)carve(128 * 128 * 2);
    unsigned short* wt2 = (unsigned short*)carve(128 * 128 * 2);
    float* dinv   = (float*)carve((size_t)N_NODES * 4);
    int*   cnt    = (int*)carve((size_t)N_NODES * 4);
    int*   rowptr = (int*)carve((size_t)(N_NODES + 1) * 4);
    int*   bsum   = (int*)carve(256 * 4);
    int*   ord    = (int*)carve((size_t)N_EDGES * 4);
    int*   esrc   = (int*)carve((size_t)N_EDGES * 4);
    float* ew2    = (float*)carve((size_t)N_EDGES * 4);
    float* enorm  = (float*)carve((size_t)N_EDGES * 4);
    (void)ws_size; (void)n_in; (void)in_sizes; (void)out_size;

    int nb = (N_NODES + 255) / 256;
    int eb = (N_EDGES + 255) / 256;

    k_zero<<<(N_NODES / 4 + 255) / 256, 256, 0, stream>>>((int4*)cnt, N_NODES / 4);
    k_prep<<<128 + (N_EDGES / 4 + 255) / 256, 256, 0, stream>>>(
        W1, W2, wt1, wt2, (const int4*)dst, cnt, (int4*)ord);
    k_scan1<<<nb, 256, 0, stream>>>(cnt, rowptr, bsum, N_NODES);
    k_scan23<<<nb, 256, 0, stream>>>(rowptr, bsum, nb, N_NODES);
    k_sg<<<GB + eb, 256, 0, stream>>>(x, wt1, hb, N_NODES,
                                      src, dst, ew, ord, rowptr, esrc, ew2);
    k_deg<<<nb, 256, 0, stream>>>(rowptr, ew2, dinv);
    k_norm<<<nb, 256, 0, stream>>>(rowptr, esrc, ew2, dinv, enorm);

    // layer-1 aggregation, head (full-occupancy gather shape)
    k_agg0<<<NSPLIT / 4, 256, 0, stream>>>((const unsigned*)hb, rowptr, esrc,
                                           enorm, dinv, b1, (unsigned*)zb, 0);
    // tail aggregation || GEMM2 over completed head rows
    k_gx<<<AGGB2 + GEMA, 256, 0, stream>>>((const unsigned*)hb, rowptr, esrc,
                                           enorm, dinv, b1, (unsigned*)zb,
                                           zb, wt2, hb2);
    // GEMM2 tail
    k_gemm2b<<<GEMB, 256, 0, stream>>>(zb, wt2, hb2);
    // layer-2 aggregation + classifier
    k_agg1<<<(N_NODES + 3) / 4, 256, 0, stream>>>((const unsigned*)hb2, rowptr, esrc,
                                                  enorm, dinv, b2, Wc, bc, out);
}

// Round 13
// 150.794 us; speedup vs baseline: 1.2989x; 1.1261x over previous
//
#include <hip/hip_runtime.h>
#include <hip/hip_bf16.h>

#define N_NODES 50000
#define N_EDGES 600000
#define NC 10
#define GB ((N_NODES + 63) / 64)
#define CNTB ((N_EDGES / 4 + 255) / 256)   // 587 count blocks

typedef __attribute__((ext_vector_type(8))) __bf16 bf16x8;
typedef __attribute__((ext_vector_type(8))) unsigned short u16x8;
typedef __attribute__((ext_vector_type(4))) float f32x4;

__device__ __forceinline__ unsigned short f2bf(float f) {
    unsigned u = __float_as_uint(f);
    u += 0x7fff + ((u >> 16) & 1);           // round-to-nearest-even
    return (unsigned short)(u >> 16);
}
__device__ __forceinline__ int rfl(int x) { return __builtin_amdgcn_readfirstlane(x); }
__device__ __forceinline__ float rflf(float x) {
    return __uint_as_float(__builtin_amdgcn_readfirstlane(__float_as_uint(x)));
}

// ---------------- prep0: W transposes + cnt zeroing (independent work) ------
__global__ void k_prep0(const float* __restrict__ W1, const float* __restrict__ W2,
                        unsigned short* __restrict__ wt1, unsigned short* __restrict__ wt2,
                        int4* __restrict__ cnt4) {
    int b = blockIdx.x;
    if (b < 128) {
        const float* W = (b < 64) ? W1 : W2;
        unsigned short* Wt = (b < 64) ? wt1 : wt2;
        int i = (b & 63) * 256 + threadIdx.x;    // 0..16383
        int n = i >> 7, k = i & 127;
        Wt[n * 128 + k] = f2bf(W[k * 128 + n]);
    } else {
        int i = (b - 128) * 256 + threadIdx.x;
        if (i < N_NODES / 4) cnt4[i] = make_int4(0, 0, 0, 0);
    }
}

// ---------------- exclusive scan (2 kernels) ----------------
__global__ void k_scan1(const int* __restrict__ cnt, int* __restrict__ rowptr,
                        int* __restrict__ bsum, int n) {
    __shared__ int sh[256];
    int t = threadIdx.x;
    int i = blockIdx.x * 256 + t;
    int v = (i < n) ? cnt[i] : 0;
    sh[t] = v;
    __syncthreads();
    for (int off = 1; off < 256; off <<= 1) {
        int x = 0;
        if (t >= off) x = sh[t - off];
        __syncthreads();
        sh[t] += x;
        __syncthreads();
    }
    if (i < n) rowptr[i] = sh[t] - v;
    if (t == 255) bsum[blockIdx.x] = sh[255];
}

__global__ void k_scan23(int* __restrict__ rowptr, const int* __restrict__ bsum,
                         int nb, int n) {
    __shared__ int sh[256];
    __shared__ int ex[256];
    int t = threadIdx.x;
    int v = (t < nb) ? bsum[t] : 0;
    sh[t] = v;
    __syncthreads();
    for (int off = 1; off < 256; off <<= 1) {
        int x = 0;
        if (t >= off) x = sh[t - off];
        __syncthreads();
        sh[t] += x;
        __syncthreads();
    }
    ex[t] = sh[t] - v;
    __syncthreads();
    int i = blockIdx.x * 256 + t;
    if (i < n) rowptr[i] += ex[blockIdx.x];
    if (blockIdx.x == 0 && t == 0) rowptr[n] = N_EDGES;
}

// ---------------- shared GEMM body (MFMA, bf16, full staging) ----------------
template <int FP32IN>
__device__ __forceinline__ void gemm_body(unsigned short* Al, unsigned short* Bl,
                                          const void* __restrict__ Xin,
                                          const unsigned short* __restrict__ Wt,
                                          unsigned short* __restrict__ Yb,
                                          int M, int row0) {
    int t = threadIdx.x;
    for (int i = t; i < 2048; i += 256) {
        int r = i >> 4, q = i & 15;
        *(u16x8*)(Bl + r * 128 + ((q ^ (r & 7)) << 3)) =
            *(const u16x8*)(Wt + r * 128 + (q << 3));
    }
    for (int i = t; i < 1024; i += 256) {
        int r = i >> 4, q = i & 15;
        int gr = row0 + r;
        u16x8 v;
        if (FP32IN) {
            const float* X = (const float*)Xin;
            if (gr < M) {
                float4 f0 = *(const float4*)(X + (size_t)gr * 128 + (q << 3));
                float4 f1 = *(const float4*)(X + (size_t)gr * 128 + (q << 3) + 4);
                v[0] = f2bf(f0.x); v[1] = f2bf(f0.y); v[2] = f2bf(f0.z); v[3] = f2bf(f0.w);
                v[4] = f2bf(f1.x); v[5] = f2bf(f1.y); v[6] = f2bf(f1.z); v[7] = f2bf(f1.w);
            } else {
#pragma unroll
                for (int j = 0; j < 8; ++j) v[j] = 0;
            }
        } else {
            const unsigned short* X = (const unsigned short*)Xin;
            if (gr < M) {
                v = *(const u16x8*)(X + (size_t)gr * 128 + (q << 3));
            } else {
#pragma unroll
                for (int j = 0; j < 8; ++j) v[j] = 0;
            }
        }
        *(u16x8*)(Al + r * 128 + ((q ^ (r & 7)) << 3)) = v;
    }
    __syncthreads();

    int l  = t & 63;
    int w  = t >> 6;
    int ar = (w << 4) + (l & 15);
    int kq = l >> 4;

    bf16x8 af[4];
#pragma unroll
    for (int s = 0; s < 4; ++s) {
        int g = ((s << 2) + kq) ^ (l & 7);
        af[s] = *(const bf16x8*)(Al + ar * 128 + (g << 3));
    }

    f32x4 acc[8];
#pragma unroll
    for (int c = 0; c < 8; ++c)
#pragma unroll
        for (int j = 0; j < 4; ++j) acc[c][j] = 0.0f;

#pragma unroll
    for (int c = 0; c < 8; ++c) {
        int br = (c << 4) + (l & 15);
#pragma unroll
        for (int s = 0; s < 4; ++s) {
            int g = ((s << 2) + kq) ^ (l & 7);
            bf16x8 bf = *(const bf16x8*)(Bl + br * 128 + (g << 3));
            acc[c] = __builtin_amdgcn_mfma_f32_16x16x32_bf16(af[s], bf, acc[c], 0, 0, 0);
        }
    }

    int orow = row0 + (w << 4) + ((l >> 4) << 2);
    int ocol = l & 15;
#pragma unroll
    for (int c = 0; c < 8; ++c) {
#pragma unroll
        for (int j = 0; j < 4; ++j) {
            int r = orow + j;
            if (r < M) Yb[(size_t)r * 128 + (c << 4) + ocol] = f2bf(acc[c][j]);
        }
    }
}

// ---------------- fused: edge count (rate-bound, FIRST) + GEMM1 -------------
__global__ __launch_bounds__(256) void k_cg(const int4* __restrict__ dst4,
                                            int* __restrict__ cnt,
                                            int4* __restrict__ ord4,
                                            const float* __restrict__ X,
                                            const unsigned short* __restrict__ Wt,
                                            unsigned short* __restrict__ Yb, int M) {
    __shared__ unsigned short Al[64 * 128];
    __shared__ unsigned short Bl[128 * 128];
    if (blockIdx.x < CNTB) {
        int i = blockIdx.x * 256 + threadIdx.x;
        if (i < N_EDGES / 4) {
            int4 d = dst4[i];
            int4 o;
            o.x = atomicAdd(&cnt[d.x], 1);
            o.y = atomicAdd(&cnt[d.y], 1);
            o.z = atomicAdd(&cnt[d.z], 1);
            o.w = atomicAdd(&cnt[d.w], 1);
            ord4[i] = o;
        }
    } else {
        gemm_body<1>(Al, Bl, X, Wt, Yb, M, (blockIdx.x - CNTB) * 64);
    }
}

// ---------------- standalone CSR scatter (full occupancy, no LDS) -----------
__global__ void k_scatter(const int* __restrict__ src, const int* __restrict__ dst,
                          const float* __restrict__ ew, const int* __restrict__ ord,
                          const int* __restrict__ rowptr,
                          int* __restrict__ esrc, float* __restrict__ ew2) {
    int e = blockIdx.x * blockDim.x + threadIdx.x;
    if (e >= N_EDGES) return;
    int pos = rowptr[dst[e]] + ord[e];
    esrc[pos] = src[e];
    ew2[pos]  = ew[e];
}

// ---------------- standalone GEMM (bf16 in, layer 2) ----------------
__global__ __launch_bounds__(256) void k_gemm_mfma(const unsigned short* __restrict__ Xb,
                                                   const unsigned short* __restrict__ Wt,
                                                   unsigned short* __restrict__ Yb, int M) {
    __shared__ unsigned short Al[64 * 128];
    __shared__ unsigned short Bl[128 * 128];
    gemm_body<0>(Al, Bl, Xb, Wt, Yb, M, blockIdx.x * 64);
}

// ---------------- per-node degree -> dinv ----------------
__global__ void k_deg(const int* __restrict__ rowptr, const float* __restrict__ ew2,
                      float* __restrict__ dinv) {
    int i = blockIdx.x * blockDim.x + threadIdx.x;
    if (i >= N_NODES) return;
    int p1 = rowptr[i + 1];
    float s = 1.0f;
    for (int p = rowptr[i]; p < p1; ++p) s += ew2[p];
    dinv[i] = rsqrtf(s);
}

// ---------------- per-node edge norms ----------------
__global__ void k_norm(const int* __restrict__ rowptr, const int* __restrict__ esrc,
                       const float* __restrict__ ew2, const float* __restrict__ dinv,
                       float* __restrict__ enorm) {
    int i = blockIdx.x * blockDim.x + threadIdx.x;
    if (i >= N_NODES) return;
    float di = dinv[i];
    int p  = rowptr[i];
    int p1 = rowptr[i + 1];
    for (; p + 4 <= p1; p += 4) {
        int s0 = esrc[p], s1 = esrc[p+1], s2 = esrc[p+2], s3 = esrc[p+3];
        float d0 = dinv[s0], d1 = dinv[s1], d2 = dinv[s2], d3 = dinv[s3];
        enorm[p]   = d0 * ew2[p]   * di;
        enorm[p+1] = d1 * ew2[p+1] * di;
        enorm[p+2] = d2 * ew2[p+2] * di;
        enorm[p+3] = d3 * ew2[p+3] * di;
    }
    for (; p < p1; ++p) enorm[p] = dinv[esrc[p]] * ew2[p] * di;
}

// ---------------- R8-proven per-node aggregation body ----------------
__device__ __forceinline__ float2 agg_row(const unsigned* __restrict__ hb,
                                          const int* __restrict__ rowptr,
                                          const int* __restrict__ esrc,
                                          const float* __restrict__ enorm,
                                          const float* __restrict__ dinv,
                                          int node, int lane) {
    int p  = rfl(rowptr[node]);
    int p1 = rfl(rowptr[node + 1]);
    float di  = dinv[node];
    float di2 = di * di;
    unsigned sv = hb[(size_t)node * 64 + lane];
    float2 acc;
    acc.x = __uint_as_float(sv << 16) * di2;
    acc.y = __uint_as_float(sv & 0xffff0000u) * di2;

    while (p + 16 <= p1) {
        int s[16]; float w[16]; unsigned v[16];
#pragma unroll
        for (int i = 0; i < 16; ++i) {
            s[i] = rfl(esrc[p + i]);
            w[i] = rflf(enorm[p + i]);
        }
#pragma unroll
        for (int i = 0; i < 16; ++i) v[i] = hb[(size_t)s[i] * 64 + lane];
#pragma unroll
        for (int i = 0; i < 16; ++i) {
            acc.x += w[i] * __uint_as_float(v[i] << 16);
            acc.y += w[i] * __uint_as_float(v[i] & 0xffff0000u);
        }
        p += 16;
    }
    while (p + 4 <= p1) {
        int s[4]; float w[4]; unsigned v[4];
#pragma unroll
        for (int i = 0; i < 4; ++i) {
            s[i] = rfl(esrc[p + i]);
            w[i] = rflf(enorm[p + i]);
        }
#pragma unroll
        for (int i = 0; i < 4; ++i) v[i] = hb[(size_t)s[i] * 64 + lane];
#pragma unroll
        for (int i = 0; i < 4; ++i) {
            acc.x += w[i] * __uint_as_float(v[i] << 16);
            acc.y += w[i] * __uint_as_float(v[i] & 0xffff0000u);
        }
        p += 4;
    }
    for (; p < p1; ++p) {
        int s = rfl(esrc[p]);
        float w = rflf(enorm[p]);
        unsigned v = hb[(size_t)s * 64 + lane];
        acc.x += w * __uint_as_float(v << 16);
        acc.y += w * __uint_as_float(v & 0xffff0000u);
    }
    return acc;
}

// ---------------- agg layer1: full grid, bf16 out ----------------
__global__ __launch_bounds__(256) void k_agg0(const unsigned* __restrict__ hb,
                                              const int* __restrict__ rowptr,
                                              const int* __restrict__ esrc,
                                              const float* __restrict__ enorm,
                                              const float* __restrict__ dinv,
                                              const float* __restrict__ bias,
                                              unsigned* __restrict__ outb) {
    int wid  = (blockIdx.x * blockDim.x + threadIdx.x) >> 6;
    int lane = threadIdx.x & 63;
    if (wid >= N_NODES) return;
    wid = rfl(wid);
    float2 acc = agg_row(hb, rowptr, esrc, enorm, dinv, wid, lane);
    float2 bv = ((const float2*)bias)[lane];
    acc.x = fmaxf(acc.x + bv.x, 0.f);
    acc.y = fmaxf(acc.y + bv.y, 0.f);
    outb[(size_t)wid * 64 + lane] = f2bf(acc.x) | ((unsigned)f2bf(acc.y) << 16);
}

// ---------------- agg layer2 + fused classifier ----------------
__global__ __launch_bounds__(256) void k_agg1(const unsigned* __restrict__ hb,
                                              const int* __restrict__ rowptr,
                                              const int* __restrict__ esrc,
                                              const float* __restrict__ enorm,
                                              const float* __restrict__ dinv,
                                              const float* __restrict__ bias,
                                              const float* __restrict__ Wc,
                                              const float* __restrict__ bc,
                                              float* __restrict__ out) {
    int wid  = (blockIdx.x * blockDim.x + threadIdx.x) >> 6;
    int lane = threadIdx.x & 63;
    if (wid >= N_NODES) return;
    wid = rfl(wid);
    float2 acc = agg_row(hb, rowptr, esrc, enorm, dinv, wid, lane);
    float2 bv = ((const float2*)bias)[lane];
    acc.x = fmaxf(acc.x + bv.x, 0.f);
    acc.y = fmaxf(acc.y + bv.y, 0.f);

    int k0 = 2 * lane;
    float r[NC];
#pragma unroll
    for (int c = 0; c < NC; ++c)
        r[c] = acc.x * Wc[k0 * NC + c] + acc.y * Wc[(k0 + 1) * NC + c];
#pragma unroll
    for (int off = 32; off; off >>= 1)
#pragma unroll
        for (int c = 0; c < NC; ++c)
            r[c] += __shfl_xor(r[c], off, 64);
    if (lane < NC) out[(size_t)wid * NC + lane] = r[lane] + bc[lane];
}

extern "C" void kernel_launch(void* const* d_in, const int* in_sizes, int n_in,
                              void* d_out, int out_size, void* d_ws, size_t ws_size,
                              hipStream_t stream) {
    const float* x   = (const float*)d_in[0];
    const int*   ei  = (const int*)d_in[1];
    const float* ew  = (const float*)d_in[2];
    const float* W1  = (const float*)d_in[3];
    const float* b1  = (const float*)d_in[4];
    const float* W2  = (const float*)d_in[5];
    const float* b2  = (const float*)d_in[6];
    const float* Wc  = (const float*)d_in[7];
    const float* bc  = (const float*)d_in[8];
    float*       out = (float*)d_out;

    const int* src = ei;
    const int* dst = ei + N_EDGES;

    size_t off = 0;
    auto carve = [&](size_t bytes) {
        void* p = (char*)d_ws + off;
        off += (bytes + 255) & ~(size_t)255;
        return p;
    };
    unsigned short* hb  = (unsigned short*)carve((size_t)N_NODES * 128 * 2); // layer1 h
    unsigned short* zb  = (unsigned short*)carve((size_t)N_NODES * 128 * 2); // relu(agg1)
    unsigned short* hb2 = (unsigned short*)carve((size_t)N_NODES * 128 * 2); // gemm2 out
    unsigned short* wt1 = (unsigned short*)carve(128 * 128 * 2);
    unsigned short* wt2 = (unsigned short*)carve(128 * 128 * 2);
    float* dinv   = (float*)carve((size_t)N_NODES * 4);
    int*   cnt    = (int*)carve((size_t)N_NODES * 4);
    int*   rowptr = (int*)carve((size_t)(N_NODES + 1) * 4);
    int*   bsum   = (int*)carve(256 * 4);
    int*   ord    = (int*)carve((size_t)N_EDGES * 4);
    int*   esrc   = (int*)carve((size_t)N_EDGES * 4);
    float* ew2    = (float*)carve((size_t)N_EDGES * 4);
    float* enorm  = (float*)carve((size_t)N_EDGES * 4);
    (void)ws_size; (void)n_in; (void)in_sizes; (void)out_size;

    int nb = (N_NODES + 255) / 256;
    int eb = (N_EDGES + 255) / 256;

    // prep: W transposes + cnt zero (one kernel, independent work)
    k_prep0<<<128 + (N_NODES / 4 + 255) / 256, 256, 0, stream>>>(W1, W2, wt1, wt2,
                                                                 (int4*)cnt);
    // count atomics (rate-bound, dispatched first) overlapped with GEMM1
    k_cg<<<CNTB + GB, 256, 0, stream>>>((const int4*)dst, cnt, (int4*)ord,
                                        x, wt1, hb, N_NODES);
    k_scan1<<<nb, 256, 0, stream>>>(cnt, rowptr, bsum, N_NODES);
    k_scan23<<<nb, 256, 0, stream>>>(rowptr, bsum, nb, N_NODES);
    k_scatter<<<eb, 256, 0, stream>>>(src, dst, ew, ord, rowptr, esrc, ew2);
    k_deg<<<nb, 256, 0, stream>>>(rowptr, ew2, dinv);
    k_norm<<<nb, 256, 0, stream>>>(rowptr, esrc, ew2, dinv, enorm);

    // layer-1 aggregation (full-occupancy R8 shape)
    k_agg0<<<(N_NODES + 3) / 4, 256, 0, stream>>>((const unsigned*)hb, rowptr, esrc,
                                                  enorm, dinv, b1, (unsigned*)zb);
    // layer-2 GEMM
    k_gemm_mfma<<<GB, 256, 0, stream>>>(zb, wt2, hb2, N_NODES);
    // layer-2 aggregation + classifier
    k_agg1<<<(N_NODES + 3) / 4, 256, 0, stream>>>((const unsigned*)hb2, rowptr, esrc,
                                                  enorm, dinv, b2, Wc, bc, out);
}